// Round 2
// baseline (3861.525 us; speedup 1.0000x reference)
//
#include <hip/hip_runtime.h>
#include <hip/hip_fp16.h>

#define N_NODES 500000
#define N_EDGES 16000000
#define NB 1954          // ceil(N_NODES/256)
#define NPB_LOG 9
#define NPB 512          // nodes per bucket
#define NBUCK 977        // ceil(N_NODES/NPB)
#define NBUCK_PAD 1024
#define CH 32768         // edges per bucket_scatter block
#define NSB 489          // ceil(N_EDGES/CH)

// sub-sort of each node's neighbor list by src slice for L2 locality:
// src < 500000 < 2^19; src>>15 in [0,15] -> 16 slices of 32768 nodes.
#define SLICE_SHIFT 15
#define NSLICE 16
#define NKEY (NPB * NSLICE)   // 8192 counters = 32 KB LDS

// phased layer kernels: 1024 co-resident blocks, 2 nodes/thread
#define GRID_BLK 1024
#define NTHREADS (GRID_BLK * 256)

// ---------- fp16 pack/unpack helpers (fp32 math everywhere else) ----------
__device__ __forceinline__ float2 up2(int p) {
    __half2 h = *reinterpret_cast<__half2*>(&p);
    return __half22float2(h);
}
__device__ __forceinline__ int pk2(float a, float b) {
    __half2 h = __floats2half2_rn(a, b);
    return *reinterpret_cast<int*>(&h);
}

// ---------- performance-only grid phase barrier (bounded spin, no deadlock) --
// arrive always; wait only while `wait` and budget not exhausted.
// Returns false on timeout (caller makes it sticky).
__device__ __forceinline__ bool grid_phase_barrier(int* bar, int idx, int budget, bool wait) {
    __hip_atomic_fetch_add(&bar[idx], 1, __ATOMIC_RELAXED, __HIP_MEMORY_SCOPE_AGENT);
    if (!wait) return false;
    int spins = 0;
    while (__hip_atomic_load(&bar[idx], __ATOMIC_RELAXED, __HIP_MEMORY_SCOPE_AGENT) < GRID_BLK) {
        if (++spins > budget) return false;
        __builtin_amdgcn_s_sleep(16);
    }
    return true;
}

// ============================================================================
// Two-level counting sort (LDS atomics) -> CSR (off, S)
// ============================================================================

__global__ void bucket_hist(const int* __restrict__ dst, int* __restrict__ ghist) {
    __shared__ int lhist[NBUCK_PAD];
    for (int t = threadIdx.x; t < NBUCK_PAD; t += 256) lhist[t] = 0;
    __syncthreads();
    int stride = gridDim.x * 256;
    for (int i = blockIdx.x * 256 + threadIdx.x; i < N_EDGES; i += stride) {
        atomicAdd(&lhist[dst[i] >> NPB_LOG], 1);
    }
    __syncthreads();
    for (int t = threadIdx.x; t < NBUCK_PAD; t += 256) {
        int c = lhist[t];
        if (c) atomicAdd(&ghist[t], c);
    }
}

__global__ void bucket_scan(int* __restrict__ gcur, int* __restrict__ bbase) {
    __shared__ int s[256];
    int t = threadIdx.x;
    int v[4], sum = 0, loc[4];
#pragma unroll
    for (int j = 0; j < 4; ++j) {
        v[j] = gcur[t * 4 + j];
        loc[j] = sum;
        sum += v[j];
    }
    s[t] = sum;
    __syncthreads();
    for (int o = 1; o < 256; o <<= 1) {
        int x = (t >= o) ? s[t - o] : 0;
        __syncthreads();
        s[t] += x;
        __syncthreads();
    }
    int excl = s[t] - sum;
#pragma unroll
    for (int j = 0; j < 4; ++j) {
        int e = excl + loc[j];
        bbase[t * 4 + j] = e;
        gcur[t * 4 + j] = e;
    }
    if (t == 255) bbase[NBUCK_PAD] = s[255];
}

__global__ void bucket_scatter(const int* __restrict__ src, const int* __restrict__ dst,
                               int* __restrict__ gcur, int* __restrict__ P) {
    __shared__ int lhist[NBUCK_PAD];
    __shared__ int lcur[NBUCK_PAD];
    for (int t = threadIdx.x; t < NBUCK_PAD; t += 256) lhist[t] = 0;
    __syncthreads();
    int e0 = blockIdx.x * CH;
    int e1 = min(e0 + CH, N_EDGES);
    for (int i = e0 + threadIdx.x; i < e1; i += 256) {
        atomicAdd(&lhist[dst[i] >> NPB_LOG], 1);
    }
    __syncthreads();
    for (int t = threadIdx.x; t < NBUCK_PAD; t += 256) {
        int c = lhist[t];
        lcur[t] = c ? atomicAdd(&gcur[t], c) : 0;
    }
    __syncthreads();
    for (int i = e0 + threadIdx.x; i < e1; i += 256) {
        int d = dst[i];
        int s = src[i];
        int b = d >> NPB_LOG;
        int pos = atomicAdd(&lcur[b], 1);
        P[pos] = ((d & (NPB - 1)) << 19) | s;
    }
}

// fine_sort: counting key = (node_in_bucket << 4) | (src >> 15).
// Per-node CSR segments, each node's neighbor list sub-ordered by src slice.
__global__ void fine_sort(const int* __restrict__ P, const int* __restrict__ bbase,
                          int* __restrict__ off, int* __restrict__ S) {
    __shared__ int hist[NKEY];   // 32 KB
    __shared__ int sscan[256];
    int t = threadIdx.x;
    int b = blockIdx.x;
    int bb = bbase[b];
    int be = bbase[b + 1];
    int node0 = b << NPB_LOG;

    for (int j = t; j < NKEY; j += 256) hist[j] = 0;
    __syncthreads();
    for (int j = bb + t; j < be; j += 256) {
        int p = P[j];
        int n = p >> 19;
        int s = p & 0x7FFFF;
        atomicAdd(&hist[(n << 4) | (s >> SLICE_SHIFT)], 1);
    }
    __syncthreads();

    // scan over 8192 counters: thread t owns keys [32t, 32t+32)
    int base = t * 32;
    int sum = 0;
#pragma unroll
    for (int j = 0; j < 32; ++j) sum += hist[base + j];
    sscan[t] = sum;
    __syncthreads();
    for (int o = 1; o < 256; o <<= 1) {
        int x = (t >= o) ? sscan[t - o] : 0;
        __syncthreads();
        sscan[t] += x;
        __syncthreads();
    }
    int run = sscan[t] - sum;
#pragma unroll
    for (int j = 0; j < 32; ++j) {
        int c = hist[base + j];
        hist[base + j] = run;
        run += c;
    }
    __syncthreads();

#pragma unroll
    for (int j = 0; j < 2; ++j) {
        int idx = t + j * 256;   // node_in_bucket
        int ng = node0 + idx;
        if (ng < N_NODES) off[ng] = bb + hist[idx << 4];
    }
    if (b == NBUCK - 1 && t == 0) off[N_NODES] = N_EDGES;
    __syncthreads();

    for (int j = bb + t; j < be; j += 256) {
        int p = P[j];
        int n = p >> 19;
        int s = p & 0x7FFFF;
        int pos = atomicAdd(&hist[(n << 4) | (s >> SLICE_SHIFT)], 1);
        S[bb + pos] = s;
    }
}

// ============================================================================
// fp16 table prep: x (fp32, 4 feats) -> xh (fp16, 8 B rows)
// ============================================================================

__global__ void convert_x(const float* __restrict__ x, int2* __restrict__ xh) {
    int i = blockIdx.x * 256 + threadIdx.x;
    if (i >= N_NODES) return;
    float4 v = ((const float4*)x)[i];
    int2 r;
    r.x = pk2(v.x, v.y);
    r.y = pk2(v.z, v.w);
    xh[i] = r;
}

// ============================================================================
// Phased fused layers: slice-synchronized gathers (per-XCD L2-resident slices)
// ============================================================================

__device__ __forceinline__ void l1_tail(int n, float deg, const float* acc,
        const float* __restrict__ x, const float* s_wl, const float* s_wr,
        const float* s_b, int* __restrict__ h1) {
    if (n >= N_NODES) return;
    float inv = 1.f / fmaxf(deg, 1.f);
    float a[4];
#pragma unroll
    for (int q = 0; q < 4; ++q) a[q] = acc[q] * inv;
    float4 xs = ((const float4*)x)[n];
    float xv[4] = {xs.x, xs.y, xs.z, xs.w};
    float r[10];
#pragma unroll
    for (int j = 0; j < 10; ++j) {
        float t = s_b[j];
#pragma unroll
        for (int kk = 0; kk < 4; ++kk)
            t += s_wl[j * 4 + kk] * a[kk] + s_wr[j * 4 + kk] * xv[kk];
        r[j] = fmaxf(t, 0.f);
    }
    int4 o0;
    o0.x = pk2(r[0], r[1]); o0.y = pk2(r[2], r[3]);
    o0.z = pk2(r[4], r[5]); o0.w = pk2(r[6], r[7]);
    *(int4*)(h1 + (long)n * 8) = o0;
    h1[(long)n * 8 + 4] = pk2(r[8], r[9]);
}

__global__ __launch_bounds__(256, 4) void fused_l1p(
        const int* __restrict__ off, const int* __restrict__ ssrc,
        const int2* __restrict__ xh, const float* __restrict__ x,
        const float* __restrict__ wl, const float* __restrict__ bl,
        const float* __restrict__ wr, int* __restrict__ h1,
        int* __restrict__ bar) {
    __shared__ float s_wl[40];
    __shared__ float s_wr[40];
    __shared__ float s_b[10];
    if (threadIdx.x < 40) {
        s_wl[threadIdx.x] = wl[threadIdx.x];
        s_wr[threadIdx.x] = wr[threadIdx.x];
    }
    if (threadIdx.x >= 64 && threadIdx.x < 74) s_b[threadIdx.x - 64] = bl[threadIdx.x - 64];
    __syncthreads();

    const int tg = blockIdx.x * 256 + threadIdx.x;
    const int n0 = tg, n1 = tg + NTHREADS;
    int k0 = off[n0], e0 = off[n0 + 1];
    int k1 = 0, e1 = 0;
    if (n1 < N_NODES) { k1 = off[n1]; e1 = off[n1 + 1]; }
    float deg0 = (float)(e0 - k0), deg1 = (float)(e1 - k1);
    int sv0 = (k0 < e0) ? ssrc[k0] : 0x7FFFFFFF;
    int sv1 = (k1 < e1) ? ssrc[k1] : 0x7FFFFFFF;
    float acc0[4] = {0.f, 0.f, 0.f, 0.f};
    float acc1[4] = {0.f, 0.f, 0.f, 0.f};

    bool coop = true;
    if (threadIdx.x == 0) coop = grid_phase_barrier(bar, 16, 300, true);
    __syncthreads();

    constexpr int PH = 8, SPP = NSLICE / PH;   // 512 KB of xh per phase
    for (int s = 0; s < PH; ++s) {
        const int lim = ((s + 1) * SPP) << SLICE_SHIFT;
        while (sv0 < lim) {
            int2 v = xh[sv0];
            ++k0; sv0 = (k0 < e0) ? ssrc[k0] : 0x7FFFFFFF;
            float2 f0 = up2(v.x), f1 = up2(v.y);
            acc0[0] += f0.x; acc0[1] += f0.y; acc0[2] += f1.x; acc0[3] += f1.y;
        }
        while (sv1 < lim) {
            int2 v = xh[sv1];
            ++k1; sv1 = (k1 < e1) ? ssrc[k1] : 0x7FFFFFFF;
            float2 f0 = up2(v.x), f1 = up2(v.y);
            acc1[0] += f0.x; acc1[1] += f0.y; acc1[2] += f1.x; acc1[3] += f1.y;
        }
        if (s < PH - 1) {
            if (threadIdx.x == 0) coop = grid_phase_barrier(bar, s, 60, coop) && coop;
            __syncthreads();
        }
    }
    l1_tail(n0, deg0, acc0, x, s_wl, s_wr, s_b, h1);
    l1_tail(n1, deg1, acc1, x, s_wl, s_wr, s_b, h1);
}

__device__ __forceinline__ void l2_tail(int n, float deg, float* acc,
        const int* __restrict__ h1, const float* s_wl, const float* s_wr,
        const float* s_b, int* __restrict__ h2) {
    if (n >= N_NODES) return;
    float inv = 1.f / fmaxf(deg, 1.f);
#pragma unroll
    for (int q = 0; q < 10; ++q) acc[q] *= inv;
    float xv[10];
    {
        const int* row = h1 + (long)n * 8;
        int4 v4 = *(const int4*)row;
        int v1 = row[4];
        float2 f0 = up2(v4.x), f1 = up2(v4.y), f2 = up2(v4.z), f3 = up2(v4.w), f4 = up2(v1);
        xv[0] = f0.x; xv[1] = f0.y; xv[2] = f1.x; xv[3] = f1.y;
        xv[4] = f2.x; xv[5] = f2.y; xv[6] = f3.x; xv[7] = f3.y;
        xv[8] = f4.x; xv[9] = f4.y;
    }
    float r[20];
#pragma unroll
    for (int j = 0; j < 20; ++j) {
        float t = s_b[j];
#pragma unroll
        for (int kk = 0; kk < 10; ++kk)
            t += s_wl[j * 10 + kk] * acc[kk] + s_wr[j * 10 + kk] * xv[kk];
        r[j] = fmaxf(t, 0.f);
    }
    int* o = h2 + (long)n * 16;
    int4 o0, o1;
    o0.x = pk2(r[0], r[1]);   o0.y = pk2(r[2], r[3]);
    o0.z = pk2(r[4], r[5]);   o0.w = pk2(r[6], r[7]);
    o1.x = pk2(r[8], r[9]);   o1.y = pk2(r[10], r[11]);
    o1.z = pk2(r[12], r[13]); o1.w = pk2(r[14], r[15]);
    *(int4*)o = o0;
    *(int4*)(o + 4) = o1;
    int2 o2;
    o2.x = pk2(r[16], r[17]); o2.y = pk2(r[18], r[19]);
    *(int2*)(o + 8) = o2;
}

__global__ __launch_bounds__(256, 4) void fused_l2p(
        const int* __restrict__ off, const int* __restrict__ ssrc,
        const int* __restrict__ h1,
        const float* __restrict__ wl, const float* __restrict__ bl,
        const float* __restrict__ wr, int* __restrict__ h2,
        int* __restrict__ bar) {
    __shared__ float s_wl[200];
    __shared__ float s_wr[200];
    __shared__ float s_b[20];
    if (threadIdx.x < 200) {
        s_wl[threadIdx.x] = wl[threadIdx.x];
        s_wr[threadIdx.x] = wr[threadIdx.x];
    }
    if (threadIdx.x >= 224 && threadIdx.x < 244) s_b[threadIdx.x - 224] = bl[threadIdx.x - 224];
    __syncthreads();

    const int tg = blockIdx.x * 256 + threadIdx.x;
    const int n0 = tg, n1 = tg + NTHREADS;
    int k0 = off[n0], e0 = off[n0 + 1];
    int k1 = 0, e1 = 0;
    if (n1 < N_NODES) { k1 = off[n1]; e1 = off[n1 + 1]; }
    float deg0 = (float)(e0 - k0), deg1 = (float)(e1 - k1);
    int sv0 = (k0 < e0) ? ssrc[k0] : 0x7FFFFFFF;
    int sv1 = (k1 < e1) ? ssrc[k1] : 0x7FFFFFFF;
    float acc0[10], acc1[10];
#pragma unroll
    for (int q = 0; q < 10; ++q) { acc0[q] = 0.f; acc1[q] = 0.f; }

    bool coop = true;
    if (threadIdx.x == 0) coop = grid_phase_barrier(bar, 16, 300, true);
    __syncthreads();

    constexpr int PH = 8, SPP = NSLICE / PH;   // 2 MB of h1 per phase
    for (int s = 0; s < PH; ++s) {
        const int lim = ((s + 1) * SPP) << SLICE_SHIFT;
        while (sv0 < lim) {
            const int* row = h1 + (long)sv0 * 8;
            int4 v4 = *(const int4*)row;
            int v1 = row[4];
            ++k0; sv0 = (k0 < e0) ? ssrc[k0] : 0x7FFFFFFF;
            float2 f0 = up2(v4.x), f1 = up2(v4.y), f2 = up2(v4.z), f3 = up2(v4.w), f4 = up2(v1);
            acc0[0] += f0.x; acc0[1] += f0.y; acc0[2] += f1.x; acc0[3] += f1.y;
            acc0[4] += f2.x; acc0[5] += f2.y; acc0[6] += f3.x; acc0[7] += f3.y;
            acc0[8] += f4.x; acc0[9] += f4.y;
        }
        while (sv1 < lim) {
            const int* row = h1 + (long)sv1 * 8;
            int4 v4 = *(const int4*)row;
            int v1 = row[4];
            ++k1; sv1 = (k1 < e1) ? ssrc[k1] : 0x7FFFFFFF;
            float2 f0 = up2(v4.x), f1 = up2(v4.y), f2 = up2(v4.z), f3 = up2(v4.w), f4 = up2(v1);
            acc1[0] += f0.x; acc1[1] += f0.y; acc1[2] += f1.x; acc1[3] += f1.y;
            acc1[4] += f2.x; acc1[5] += f2.y; acc1[6] += f3.x; acc1[7] += f3.y;
            acc1[8] += f4.x; acc1[9] += f4.y;
        }
        if (s < PH - 1) {
            if (threadIdx.x == 0) coop = grid_phase_barrier(bar, s, 60, coop) && coop;
            __syncthreads();
        }
    }
    l2_tail(n0, deg0, acc0, h1, s_wl, s_wr, s_b, h2);
    l2_tail(n1, deg1, acc1, h1, s_wl, s_wr, s_b, h2);
}

__device__ __forceinline__ void l3_tail(int n, float deg, float* acc,
        const int* __restrict__ h2, const float* s_wl, const float* s_wr,
        const float* s_b, const float* s_wc, const float* s_bc,
        float* __restrict__ out) {
    if (n >= N_NODES) return;
    float inv = 1.f / fmaxf(deg, 1.f);
#pragma unroll
    for (int q = 0; q < 20; ++q) acc[q] *= inv;
    float xv[20];
    {
        const int* row = h2 + (long)n * 16;
        int4 va = *(const int4*)row;
        int4 vb = *(const int4*)(row + 4);
        int2 vc = *(const int2*)(row + 8);
        float2 f;
        f = up2(va.x); xv[0] = f.x; xv[1] = f.y;
        f = up2(va.y); xv[2] = f.x; xv[3] = f.y;
        f = up2(va.z); xv[4] = f.x; xv[5] = f.y;
        f = up2(va.w); xv[6] = f.x; xv[7] = f.y;
        f = up2(vb.x); xv[8] = f.x; xv[9] = f.y;
        f = up2(vb.y); xv[10] = f.x; xv[11] = f.y;
        f = up2(vb.z); xv[12] = f.x; xv[13] = f.y;
        f = up2(vb.w); xv[14] = f.x; xv[15] = f.y;
        f = up2(vc.x); xv[16] = f.x; xv[17] = f.y;
        f = up2(vc.y); xv[18] = f.x; xv[19] = f.y;
    }
    float h3[20];
#pragma unroll
    for (int j = 0; j < 20; ++j) {
        float r = s_b[j];
#pragma unroll
        for (int kk = 0; kk < 20; ++kk)
            r += s_wl[j * 20 + kk] * acc[kk] + s_wr[j * 20 + kk] * xv[kk];
        h3[j] = fmaxf(r, 0.f);
    }
#pragma unroll
    for (int j = 0; j < 8; ++j) {
        float r = s_bc[j];
#pragma unroll
        for (int kk = 0; kk < 20; ++kk) r += s_wc[j * 20 + kk] * h3[kk];
        out[(long)n * 8 + j] = r;
    }
}

__global__ __launch_bounds__(256, 4) void fused_l3p(
        const int* __restrict__ off, const int* __restrict__ ssrc,
        const int* __restrict__ h2,
        const float* __restrict__ w3l, const float* __restrict__ b3,
        const float* __restrict__ w3r,
        const float* __restrict__ wc, const float* __restrict__ bc,
        float* __restrict__ out, int* __restrict__ bar) {
    __shared__ float s_wl[400];
    __shared__ float s_wr[400];
    __shared__ float s_b[20];
    __shared__ float s_wc[160];
    __shared__ float s_bc[8];
    for (int t = threadIdx.x; t < 400; t += 256) {
        s_wl[t] = w3l[t];
        s_wr[t] = w3r[t];
    }
    if (threadIdx.x < 160) s_wc[threadIdx.x] = wc[threadIdx.x];
    if (threadIdx.x >= 192 && threadIdx.x < 212) s_b[threadIdx.x - 192] = b3[threadIdx.x - 192];
    if (threadIdx.x >= 224 && threadIdx.x < 232) s_bc[threadIdx.x - 224] = bc[threadIdx.x - 224];
    __syncthreads();

    const int tg = blockIdx.x * 256 + threadIdx.x;
    const int n0 = tg, n1 = tg + NTHREADS;
    int k0 = off[n0], e0 = off[n0 + 1];
    int k1 = 0, e1 = 0;
    if (n1 < N_NODES) { k1 = off[n1]; e1 = off[n1 + 1]; }
    float deg0 = (float)(e0 - k0), deg1 = (float)(e1 - k1);
    int sv0 = (k0 < e0) ? ssrc[k0] : 0x7FFFFFFF;
    int sv1 = (k1 < e1) ? ssrc[k1] : 0x7FFFFFFF;
    float acc0[20], acc1[20];
#pragma unroll
    for (int q = 0; q < 20; ++q) { acc0[q] = 0.f; acc1[q] = 0.f; }

    bool coop = true;
    if (threadIdx.x == 0) coop = grid_phase_barrier(bar, 16, 300, true);
    __syncthreads();

    constexpr int PH = 16;   // 2 MB of h2 per phase
    for (int s = 0; s < PH; ++s) {
        const int lim = (s + 1) << SLICE_SHIFT;
        while (sv0 < lim) {
            const int* row = h2 + (long)sv0 * 16;
            int4 va = *(const int4*)row;
            int4 vb = *(const int4*)(row + 4);
            int2 vc = *(const int2*)(row + 8);
            ++k0; sv0 = (k0 < e0) ? ssrc[k0] : 0x7FFFFFFF;
            float2 f;
            f = up2(va.x); acc0[0] += f.x; acc0[1] += f.y;
            f = up2(va.y); acc0[2] += f.x; acc0[3] += f.y;
            f = up2(va.z); acc0[4] += f.x; acc0[5] += f.y;
            f = up2(va.w); acc0[6] += f.x; acc0[7] += f.y;
            f = up2(vb.x); acc0[8] += f.x; acc0[9] += f.y;
            f = up2(vb.y); acc0[10] += f.x; acc0[11] += f.y;
            f = up2(vb.z); acc0[12] += f.x; acc0[13] += f.y;
            f = up2(vb.w); acc0[14] += f.x; acc0[15] += f.y;
            f = up2(vc.x); acc0[16] += f.x; acc0[17] += f.y;
            f = up2(vc.y); acc0[18] += f.x; acc0[19] += f.y;
        }
        while (sv1 < lim) {
            const int* row = h2 + (long)sv1 * 16;
            int4 va = *(const int4*)row;
            int4 vb = *(const int4*)(row + 4);
            int2 vc = *(const int2*)(row + 8);
            ++k1; sv1 = (k1 < e1) ? ssrc[k1] : 0x7FFFFFFF;
            float2 f;
            f = up2(va.x); acc1[0] += f.x; acc1[1] += f.y;
            f = up2(va.y); acc1[2] += f.x; acc1[3] += f.y;
            f = up2(va.z); acc1[4] += f.x; acc1[5] += f.y;
            f = up2(va.w); acc1[6] += f.x; acc1[7] += f.y;
            f = up2(vb.x); acc1[8] += f.x; acc1[9] += f.y;
            f = up2(vb.y); acc1[10] += f.x; acc1[11] += f.y;
            f = up2(vb.z); acc1[12] += f.x; acc1[13] += f.y;
            f = up2(vb.w); acc1[14] += f.x; acc1[15] += f.y;
            f = up2(vc.x); acc1[16] += f.x; acc1[17] += f.y;
            f = up2(vc.y); acc1[18] += f.x; acc1[19] += f.y;
        }
        if (s < PH - 1) {
            if (threadIdx.x == 0) coop = grid_phase_barrier(bar, s, 60, coop) && coop;
            __syncthreads();
        }
    }
    l3_tail(n0, deg0, acc0, h2, s_wl, s_wr, s_b, s_wc, s_bc, out);
    l3_tail(n1, deg1, acc1, h2, s_wl, s_wr, s_b, s_wc, s_bc, out);
}

// ============================================================================
// Path B (fallback, small ws): float-atomic version
// ============================================================================

__global__ void deg_kernel(const int* __restrict__ dst, int* __restrict__ deg) {
    int i = blockIdx.x * blockDim.x + threadIdx.x;
    if (i < N_EDGES) atomicAdd(&deg[dst[i]], 1);
}

template <int F>
__global__ void edge_agg(const int* __restrict__ src, const int* __restrict__ dst,
                         const float* __restrict__ h, float* __restrict__ agg) {
    int i = blockIdx.x * blockDim.x + threadIdx.x;
    if (i >= N_EDGES) return;
    int s = src[i];
    int d = dst[i];
    const float* hs = h + (long)s * F;
    float* ad = agg + (long)d * F;
#pragma unroll
    for (int f = 0; f < F; ++f) atomicAdd(&ad[f], hs[f]);
}

template <int FIN, int FOUT>
__global__ void node_apply(const float* __restrict__ agg, const float* __restrict__ hin,
                           const int* __restrict__ deg, const float* __restrict__ wl,
                           const float* __restrict__ bl, const float* __restrict__ wr,
                           float* __restrict__ hout) {
    __shared__ float s_wl[FOUT * FIN];
    __shared__ float s_wr[FOUT * FIN];
    __shared__ float s_b[FOUT];
    for (int t = threadIdx.x; t < FOUT * FIN; t += blockDim.x) {
        s_wl[t] = wl[t];
        s_wr[t] = wr[t];
    }
    for (int t = threadIdx.x; t < FOUT; t += blockDim.x) s_b[t] = bl[t];
    __syncthreads();
    int i = blockIdx.x * blockDim.x + threadIdx.x;
    if (i >= N_NODES) return;
    float inv = 1.0f / fmaxf((float)deg[i], 1.0f);
    float a[FIN], xv[FIN];
#pragma unroll
    for (int kk = 0; kk < FIN; ++kk) {
        a[kk] = agg[(long)i * FIN + kk] * inv;
        xv[kk] = hin[(long)i * FIN + kk];
    }
#pragma unroll
    for (int j = 0; j < FOUT; ++j) {
        float r = s_b[j];
#pragma unroll
        for (int kk = 0; kk < FIN; ++kk) r += s_wl[j * FIN + kk] * a[kk] + s_wr[j * FIN + kk] * xv[kk];
        hout[(long)i * FOUT + j] = fmaxf(r, 0.f);
    }
}

__global__ void node_final_old(const float* __restrict__ agg, const float* __restrict__ hin,
                               const int* __restrict__ deg, const float* __restrict__ w3l,
                               const float* __restrict__ b3, const float* __restrict__ w3r,
                               const float* __restrict__ wc, const float* __restrict__ bc,
                               float* __restrict__ out) {
    __shared__ float s_wl[400];
    __shared__ float s_wr[400];
    __shared__ float s_b[20];
    __shared__ float s_wc[160];
    __shared__ float s_bc[8];
    for (int t = threadIdx.x; t < 400; t += blockDim.x) {
        s_wl[t] = w3l[t];
        s_wr[t] = w3r[t];
    }
    for (int t = threadIdx.x; t < 160; t += blockDim.x) s_wc[t] = wc[t];
    for (int t = threadIdx.x; t < 20; t += blockDim.x) s_b[t] = b3[t];
    for (int t = threadIdx.x; t < 8; t += blockDim.x) s_bc[t] = bc[t];
    __syncthreads();
    int i = blockIdx.x * blockDim.x + threadIdx.x;
    if (i >= N_NODES) return;
    float inv = 1.0f / fmaxf((float)deg[i], 1.0f);
    float a[20], xv[20];
#pragma unroll
    for (int kk = 0; kk < 20; ++kk) {
        a[kk] = agg[(long)i * 20 + kk] * inv;
        xv[kk] = hin[(long)i * 20 + kk];
    }
    float h3[20];
#pragma unroll
    for (int j = 0; j < 20; ++j) {
        float r = s_b[j];
#pragma unroll
        for (int kk = 0; kk < 20; ++kk) r += s_wl[j * 20 + kk] * a[kk] + s_wr[j * 20 + kk] * xv[kk];
        h3[j] = fmaxf(r, 0.f);
    }
#pragma unroll
    for (int j = 0; j < 8; ++j) {
        float r = s_bc[j];
#pragma unroll
        for (int kk = 0; kk < 20; ++kk) r += s_wc[j * 20 + kk] * h3[kk];
        out[(long)i * 8 + j] = r;
    }
}

// ============================================================================

extern "C" void kernel_launch(void* const* d_in, const int* in_sizes, int n_in,
                              void* d_out, int out_size, void* d_ws, size_t ws_size,
                              hipStream_t stream) {
    const float* x = (const float*)d_in[0];
    const int* ei = (const int*)d_in[1];  // [2, E]: src row then dst row
    const float* w1l = (const float*)d_in[2];
    const float* b1 = (const float*)d_in[3];
    const float* w1r = (const float*)d_in[4];
    const float* w2l = (const float*)d_in[5];
    const float* b2 = (const float*)d_in[6];
    const float* w2r = (const float*)d_in[7];
    const float* w3l = (const float*)d_in[8];
    const float* b3 = (const float*)d_in[9];
    const float* w3r = (const float*)d_in[10];
    const float* wc = (const float*)d_in[11];
    const float* bc = (const float*)d_in[12];
    float* out = (float*)d_out;

    const int* src = ei;
    const int* dst = ei + N_EDGES;

    const int BT = 256;
    dim3 blk(BT);
    dim3 egrid((N_EDGES + BT - 1) / BT);
    dim3 ngrid(NB);

    // ---- Path A v6 layout (bytes):
    // off    [0,          2,000,128)   500001 ints (padded)
    // bbase  [2,000,128,  2,004,352)   1025 ints (padded)
    // gcur   [2,004,352,  2,008,448)   1024 ints (reused as barrier slots)
    // P      [2,008,448,  66,008,448)  16M packed ints (dead after fine_sort)
    //   xh   [2,008,448,  6,008,448)   overlay: 500K x 8 B fp16 rows
    //   h1   [6,008,448, 22,008,448)   overlay: 500K x 32 B fp16 rows
    //   h2   [22,008,448, 54,008,448)  overlay: 500K x 64 B fp16 rows
    // S      [66,008,448, 130,008,448) 16M sorted src
    const size_t NEED_A = 130008448;

    if (ws_size >= NEED_A) {
        char* ws = (char*)d_ws;
        int* off = (int*)ws;
        int* bbase = (int*)(ws + 2000128);
        int* gcur = (int*)(ws + 2004352);
        int* P = (int*)(ws + 2008448);
        int2* xh = (int2*)(ws + 2008448);
        int* h1 = (int*)(ws + 6008448);
        int* h2 = (int*)(ws + 22008448);
        int* S = (int*)(ws + 66008448);

        hipMemsetAsync(gcur, 0, NBUCK_PAD * sizeof(int), stream);
        bucket_hist<<<1024, blk, 0, stream>>>(dst, gcur);
        bucket_scan<<<1, blk, 0, stream>>>(gcur, bbase);
        bucket_scatter<<<NSB, blk, 0, stream>>>(src, dst, gcur, P);
        fine_sort<<<NBUCK, blk, 0, stream>>>(P, bbase, off, S);

        // reuse gcur as barrier arrays (zeroed): l1 at +0, l2 at +32, l3 at +64
        hipMemsetAsync(gcur, 0, 128 * sizeof(int), stream);

        convert_x<<<ngrid, blk, 0, stream>>>(x, xh);
        fused_l1p<<<GRID_BLK, blk, 0, stream>>>(off, S, xh, x, w1l, b1, w1r, h1, gcur);
        fused_l2p<<<GRID_BLK, blk, 0, stream>>>(off, S, h1, w2l, b2, w2r, h2, gcur + 32);
        fused_l3p<<<GRID_BLK, blk, 0, stream>>>(off, S, h2, w3l, b3, w3r, wc, bc, out, gcur + 64);
    } else {
        // fallback: float-atomic path (needs 102 MB)
        char* ws = (char*)d_ws;
        int* deg = (int*)ws;
        float* agg = (float*)(ws + 2000000);
        float* h1 = (float*)(ws + 42000000);
        float* h2 = (float*)(ws + 62000000);

        hipMemsetAsync(deg, 0, (size_t)N_NODES * sizeof(int), stream);
        deg_kernel<<<egrid, blk, 0, stream>>>(dst, deg);

        hipMemsetAsync(agg, 0, (size_t)N_NODES * 4 * sizeof(float), stream);
        edge_agg<4><<<egrid, blk, 0, stream>>>(src, dst, x, agg);
        node_apply<4, 10><<<ngrid, blk, 0, stream>>>(agg, x, deg, w1l, b1, w1r, h1);

        hipMemsetAsync(agg, 0, (size_t)N_NODES * 10 * sizeof(float), stream);
        edge_agg<10><<<egrid, blk, 0, stream>>>(src, dst, h1, agg);
        node_apply<10, 20><<<ngrid, blk, 0, stream>>>(agg, h1, deg, w2l, b2, w2r, h2);

        hipMemsetAsync(agg, 0, (size_t)N_NODES * 20 * sizeof(float), stream);
        edge_agg<20><<<egrid, blk, 0, stream>>>(src, dst, h2, agg);
        node_final_old<<<ngrid, blk, 0, stream>>>(agg, h2, deg, w3l, b3, w3r, wc, bc, out);
    }
}

// Round 3
// 1652.018 us; speedup vs baseline: 2.3375x; 2.3375x over previous
//
#include <hip/hip_runtime.h>
#include <hip/hip_fp16.h>

#define N_NODES 500000
#define N_EDGES 16000000
#define NB 1954          // ceil(N_NODES/256)
#define NPB_LOG 9
#define NPB 512          // nodes per bucket
#define NBUCK 977        // ceil(N_NODES/NPB)
#define NBUCK_PAD 1024
#define CH 32768         // edges per bucket_scatter block
#define NSB 489          // ceil(N_EDGES/CH)

// sub-sort of each node's neighbor list by src slice for L2 locality:
// src < 500000 < 2^19; src>>15 in [0,15] -> 16 slices of 32768 nodes.
#define SLICE_SHIFT 15
#define NSLICE 16
#define NKEY (NPB * NSLICE)   // 8192 counters = 32 KB LDS

// phased layer kernels: 1024 co-resident blocks (4/CU), 2 nodes per thread
#define GRID_BLK 1024
#define HALF_T (GRID_BLK * 256)   // 262144

// distributed two-level barrier: 16 sub-counters (128 B apart) + master + flag
#define BAR_SUBC 16
#define BAR_SUBQ (GRID_BLK / BAR_SUBC)   // 64 arrivals per sub-counter
#define BAR_REC_INTS 1024                // 4 KB per barrier record
#define BAR_MASTER 512
#define BAR_FLAG 544
#define ENTRY_BUDGET 1500
#define PHASE_BUDGET 400

// ---------- fp16 pack/unpack helpers (fp32 math everywhere else) ----------
__device__ __forceinline__ float2 up2(int p) {
    __half2 h = *reinterpret_cast<__half2*>(&p);
    return __half22float2(h);
}
__device__ __forceinline__ int pk2(float a, float b) {
    __half2 h = __floats2half2_rn(a, b);
    return *reinterpret_cast<int*>(&h);
}

// ---------- performance-only distributed barrier (bounded spin) ------------
__device__ __forceinline__ void barrier_arrive(int* rec, int bid) {
    int r = __hip_atomic_fetch_add(&rec[(bid & (BAR_SUBC - 1)) * 32], 1,
                                   __ATOMIC_RELAXED, __HIP_MEMORY_SCOPE_AGENT);
    if (r == BAR_SUBQ - 1) {
        int mr = __hip_atomic_fetch_add(&rec[BAR_MASTER], 1,
                                        __ATOMIC_RELAXED, __HIP_MEMORY_SCOPE_AGENT);
        if (mr == BAR_SUBC - 1)
            __hip_atomic_store(&rec[BAR_FLAG], 1,
                               __ATOMIC_RELAXED, __HIP_MEMORY_SCOPE_AGENT);
    }
}
__device__ __forceinline__ bool barrier_wait(int* rec, int budget) {
    int spins = 0;
    while (__hip_atomic_load(&rec[BAR_FLAG],
                             __ATOMIC_RELAXED, __HIP_MEMORY_SCOPE_AGENT) == 0) {
        if (++spins > budget) return false;
        __builtin_amdgcn_s_sleep(8);
    }
    return true;
}

// ============================================================================
// Two-level counting sort (LDS atomics) -> CSR (off, S)
// ============================================================================

__global__ void bucket_hist(const int* __restrict__ dst, int* __restrict__ ghist) {
    __shared__ int lhist[NBUCK_PAD];
    for (int t = threadIdx.x; t < NBUCK_PAD; t += 256) lhist[t] = 0;
    __syncthreads();
    int stride = gridDim.x * 256;
    for (int i = blockIdx.x * 256 + threadIdx.x; i < N_EDGES; i += stride) {
        atomicAdd(&lhist[dst[i] >> NPB_LOG], 1);
    }
    __syncthreads();
    for (int t = threadIdx.x; t < NBUCK_PAD; t += 256) {
        int c = lhist[t];
        if (c) atomicAdd(&ghist[t], c);
    }
}

__global__ void bucket_scan(int* __restrict__ gcur, int* __restrict__ bbase) {
    __shared__ int s[256];
    int t = threadIdx.x;
    int v[4], sum = 0, loc[4];
#pragma unroll
    for (int j = 0; j < 4; ++j) {
        v[j] = gcur[t * 4 + j];
        loc[j] = sum;
        sum += v[j];
    }
    s[t] = sum;
    __syncthreads();
    for (int o = 1; o < 256; o <<= 1) {
        int x = (t >= o) ? s[t - o] : 0;
        __syncthreads();
        s[t] += x;
        __syncthreads();
    }
    int excl = s[t] - sum;
#pragma unroll
    for (int j = 0; j < 4; ++j) {
        int e = excl + loc[j];
        bbase[t * 4 + j] = e;
        gcur[t * 4 + j] = e;
    }
    if (t == 255) bbase[NBUCK_PAD] = s[255];
}

__global__ void bucket_scatter(const int* __restrict__ src, const int* __restrict__ dst,
                               int* __restrict__ gcur, int* __restrict__ P) {
    __shared__ int lhist[NBUCK_PAD];
    __shared__ int lcur[NBUCK_PAD];
    for (int t = threadIdx.x; t < NBUCK_PAD; t += 256) lhist[t] = 0;
    __syncthreads();
    int e0 = blockIdx.x * CH;
    int e1 = min(e0 + CH, N_EDGES);
    for (int i = e0 + threadIdx.x; i < e1; i += 256) {
        atomicAdd(&lhist[dst[i] >> NPB_LOG], 1);
    }
    __syncthreads();
    for (int t = threadIdx.x; t < NBUCK_PAD; t += 256) {
        int c = lhist[t];
        lcur[t] = c ? atomicAdd(&gcur[t], c) : 0;
    }
    __syncthreads();
    for (int i = e0 + threadIdx.x; i < e1; i += 256) {
        int d = dst[i];
        int s = src[i];
        int b = d >> NPB_LOG;
        int pos = atomicAdd(&lcur[b], 1);
        P[pos] = ((d & (NPB - 1)) << 19) | s;
    }
}

// fine_sort: counting key = (node_in_bucket << 4) | (src >> 15).
// Per-node CSR segments, each node's neighbor list sub-ordered by src slice.
__global__ void fine_sort(const int* __restrict__ P, const int* __restrict__ bbase,
                          int* __restrict__ off, int* __restrict__ S) {
    __shared__ int hist[NKEY];   // 32 KB
    __shared__ int sscan[256];
    int t = threadIdx.x;
    int b = blockIdx.x;
    int bb = bbase[b];
    int be = bbase[b + 1];
    int node0 = b << NPB_LOG;

    for (int j = t; j < NKEY; j += 256) hist[j] = 0;
    __syncthreads();
    for (int j = bb + t; j < be; j += 256) {
        int p = P[j];
        int n = p >> 19;
        int s = p & 0x7FFFF;
        atomicAdd(&hist[(n << 4) | (s >> SLICE_SHIFT)], 1);
    }
    __syncthreads();

    // scan over 8192 counters: thread t owns keys [32t, 32t+32)
    int base = t * 32;
    int sum = 0;
#pragma unroll
    for (int j = 0; j < 32; ++j) sum += hist[base + j];
    sscan[t] = sum;
    __syncthreads();
    for (int o = 1; o < 256; o <<= 1) {
        int x = (t >= o) ? sscan[t - o] : 0;
        __syncthreads();
        sscan[t] += x;
        __syncthreads();
    }
    int run = sscan[t] - sum;
#pragma unroll
    for (int j = 0; j < 32; ++j) {
        int c = hist[base + j];
        hist[base + j] = run;
        run += c;
    }
    __syncthreads();

#pragma unroll
    for (int j = 0; j < 2; ++j) {
        int idx = t + j * 256;   // node_in_bucket
        int ng = node0 + idx;
        if (ng < N_NODES) off[ng] = bb + hist[idx << 4];
    }
    if (b == NBUCK - 1 && t == 0) off[N_NODES] = N_EDGES;
    __syncthreads();

    for (int j = bb + t; j < be; j += 256) {
        int p = P[j];
        int n = p >> 19;
        int s = p & 0x7FFFF;
        int pos = atomicAdd(&hist[(n << 4) | (s >> SLICE_SHIFT)], 1);
        S[bb + pos] = s;
    }
}

// ============================================================================
// fp16 table prep: x (fp32, 4 feats) -> xh (fp16, 8 B rows)
// ============================================================================

__global__ void convert_x(const float* __restrict__ x, int2* __restrict__ xh) {
    int i = blockIdx.x * 256 + threadIdx.x;
    if (i >= N_NODES) return;
    float4 v = ((const float4*)x)[i];
    int2 r;
    r.x = pk2(v.x, v.y);
    r.y = pk2(v.z, v.w);
    xh[i] = r;
}

// ============================================================================
// Layer 1 (unphased, round-1 form): xh table is 4 MB ~ one XCD L2
// ============================================================================

__global__ __launch_bounds__(256, 4) void fused_l1(
        const int* __restrict__ off, const int* __restrict__ ssrc,
        const int2* __restrict__ xh, const float* __restrict__ x,
        const float* __restrict__ wl, const float* __restrict__ bl,
        const float* __restrict__ wr, int* __restrict__ h1) {
    __shared__ float s_wl[40];
    __shared__ float s_wr[40];
    __shared__ float s_b[10];
    if (threadIdx.x < 40) {
        s_wl[threadIdx.x] = wl[threadIdx.x];
        s_wr[threadIdx.x] = wr[threadIdx.x];
    }
    if (threadIdx.x >= 64 && threadIdx.x < 74) s_b[threadIdx.x - 64] = bl[threadIdx.x - 64];
    __syncthreads();

    int i = blockIdx.x * 256 + threadIdx.x;
    if (i >= N_NODES) return;

    int b = off[i], e = off[i + 1];
    constexpr int UN = 8;

    float acc[4] = {0.f, 0.f, 0.f, 0.f};

    int k = b;
    for (; k + UN - 1 < e; k += UN) {
        int sidx[UN];
#pragma unroll
        for (int u = 0; u < UN; ++u) sidx[u] = ssrc[k + u];
        int2 v[UN];
#pragma unroll
        for (int u = 0; u < UN; ++u) v[u] = xh[sidx[u]];
#pragma unroll
        for (int u = 0; u < UN; ++u) {
            float2 f0 = up2(v[u].x), f1 = up2(v[u].y);
            acc[0] += f0.x; acc[1] += f0.y; acc[2] += f1.x; acc[3] += f1.y;
        }
    }
    for (; k < e; ++k) {
        int2 v = xh[ssrc[k]];
        float2 f0 = up2(v.x), f1 = up2(v.y);
        acc[0] += f0.x; acc[1] += f0.y; acc[2] += f1.x; acc[3] += f1.y;
    }

    float inv = 1.f / fmaxf((float)(e - b), 1.f);
#pragma unroll
    for (int q = 0; q < 4; ++q) acc[q] *= inv;

    float4 xs = ((const float4*)x)[i];
    float xv[4] = {xs.x, xs.y, xs.z, xs.w};

    float r[10];
#pragma unroll
    for (int j = 0; j < 10; ++j) {
        float t = s_b[j];
#pragma unroll
        for (int kk = 0; kk < 4; ++kk) {
            t += s_wl[j * 4 + kk] * acc[kk] + s_wr[j * 4 + kk] * xv[kk];
        }
        r[j] = fmaxf(t, 0.f);
    }
    int4 o0;
    o0.x = pk2(r[0], r[1]); o0.y = pk2(r[2], r[3]);
    o0.z = pk2(r[4], r[5]); o0.w = pk2(r[6], r[7]);
    *(int4*)(h1 + (long)i * 8) = o0;
    h1[(long)i * 8 + 4] = pk2(r[8], r[9]);
}

// ============================================================================
// Phased layers 2 & 3: batch-of-4 MLP scan inside slice phases
// ============================================================================

// scan one cursor's edges that fall below `lim`, batched 4-wide.
// Prefix property: edges are slice-sorted within each node segment.
__device__ __forceinline__ void l2_scan_phase(int& k, const int e, const int lim,
        const int* __restrict__ ssrc, const int* __restrict__ h1, float* acc) {
    while (k < e) {
        int sidx[4];
#pragma unroll
        for (int u = 0; u < 4; ++u)
            sidx[u] = (k + u < e) ? ssrc[k + u] : 0x7FFFFFFF;
        int m = (sidx[0] < lim) + (sidx[1] < lim) + (sidx[2] < lim) + (sidx[3] < lim);
        if (m == 0) return;
        int4 v4[4];
        int v1[4];
#pragma unroll
        for (int u = 0; u < 4; ++u) {
            if (u < m) {
                const int* row = h1 + (long)sidx[u] * 8;
                v4[u] = *(const int4*)row;
                v1[u] = row[4];
            }
        }
#pragma unroll
        for (int u = 0; u < 4; ++u) {
            if (u < m) {
                float2 f0 = up2(v4[u].x), f1 = up2(v4[u].y), f2 = up2(v4[u].z),
                       f3 = up2(v4[u].w), f4 = up2(v1[u]);
                acc[0] += f0.x; acc[1] += f0.y; acc[2] += f1.x; acc[3] += f1.y;
                acc[4] += f2.x; acc[5] += f2.y; acc[6] += f3.x; acc[7] += f3.y;
                acc[8] += f4.x; acc[9] += f4.y;
            }
        }
        k += m;
        if (m < 4) return;
    }
}

__device__ __forceinline__ void l3_scan_phase(int& k, const int e, const int lim,
        const int* __restrict__ ssrc, const int* __restrict__ h2, float* acc) {
    while (k < e) {
        int sidx[4];
#pragma unroll
        for (int u = 0; u < 4; ++u)
            sidx[u] = (k + u < e) ? ssrc[k + u] : 0x7FFFFFFF;
        int m = (sidx[0] < lim) + (sidx[1] < lim) + (sidx[2] < lim) + (sidx[3] < lim);
        if (m == 0) return;
        int4 va[4], vb[4];
        int2 vc[4];
#pragma unroll
        for (int u = 0; u < 4; ++u) {
            if (u < m) {
                const int* row = h2 + (long)sidx[u] * 16;
                va[u] = *(const int4*)row;
                vb[u] = *(const int4*)(row + 4);
                vc[u] = *(const int2*)(row + 8);
            }
        }
#pragma unroll
        for (int u = 0; u < 4; ++u) {
            if (u < m) {
                float2 f;
                f = up2(va[u].x); acc[0] += f.x; acc[1] += f.y;
                f = up2(va[u].y); acc[2] += f.x; acc[3] += f.y;
                f = up2(va[u].z); acc[4] += f.x; acc[5] += f.y;
                f = up2(va[u].w); acc[6] += f.x; acc[7] += f.y;
                f = up2(vb[u].x); acc[8] += f.x; acc[9] += f.y;
                f = up2(vb[u].y); acc[10] += f.x; acc[11] += f.y;
                f = up2(vb[u].z); acc[12] += f.x; acc[13] += f.y;
                f = up2(vb[u].w); acc[14] += f.x; acc[15] += f.y;
                f = up2(vc[u].x); acc[16] += f.x; acc[17] += f.y;
                f = up2(vc[u].y); acc[18] += f.x; acc[19] += f.y;
            }
        }
        k += m;
        if (m < 4) return;
    }
}

__device__ __forceinline__ void l2_tail(int n, float deg, float* acc,
        const int* __restrict__ h1, const float* s_wl, const float* s_wr,
        const float* s_b, int* __restrict__ h2) {
    if (n >= N_NODES) return;
    float inv = 1.f / fmaxf(deg, 1.f);
#pragma unroll
    for (int q = 0; q < 10; ++q) acc[q] *= inv;
    float xv[10];
    {
        const int* row = h1 + (long)n * 8;
        int4 v4 = *(const int4*)row;
        int v1 = row[4];
        float2 f0 = up2(v4.x), f1 = up2(v4.y), f2 = up2(v4.z), f3 = up2(v4.w), f4 = up2(v1);
        xv[0] = f0.x; xv[1] = f0.y; xv[2] = f1.x; xv[3] = f1.y;
        xv[4] = f2.x; xv[5] = f2.y; xv[6] = f3.x; xv[7] = f3.y;
        xv[8] = f4.x; xv[9] = f4.y;
    }
    float r[20];
#pragma unroll
    for (int j = 0; j < 20; ++j) {
        float t = s_b[j];
#pragma unroll
        for (int kk = 0; kk < 10; ++kk)
            t += s_wl[j * 10 + kk] * acc[kk] + s_wr[j * 10 + kk] * xv[kk];
        r[j] = fmaxf(t, 0.f);
    }
    int* o = h2 + (long)n * 16;
    int4 o0, o1;
    o0.x = pk2(r[0], r[1]);   o0.y = pk2(r[2], r[3]);
    o0.z = pk2(r[4], r[5]);   o0.w = pk2(r[6], r[7]);
    o1.x = pk2(r[8], r[9]);   o1.y = pk2(r[10], r[11]);
    o1.z = pk2(r[12], r[13]); o1.w = pk2(r[14], r[15]);
    *(int4*)o = o0;
    *(int4*)(o + 4) = o1;
    int2 o2;
    o2.x = pk2(r[16], r[17]); o2.y = pk2(r[18], r[19]);
    *(int2*)(o + 8) = o2;
}

__global__ __launch_bounds__(256, 4) void fused_l2p(
        const int* __restrict__ off, const int* __restrict__ ssrc,
        const int* __restrict__ h1,
        const float* __restrict__ wl, const float* __restrict__ bl,
        const float* __restrict__ wr, int* __restrict__ h2,
        int* __restrict__ bar) {
    __shared__ float s_wl[200];
    __shared__ float s_wr[200];
    __shared__ float s_b[20];
    if (threadIdx.x < 200) {
        s_wl[threadIdx.x] = wl[threadIdx.x];
        s_wr[threadIdx.x] = wr[threadIdx.x];
    }
    if (threadIdx.x >= 224 && threadIdx.x < 244) s_b[threadIdx.x - 224] = bl[threadIdx.x - 224];
    __syncthreads();

    const int tg = blockIdx.x * 256 + threadIdx.x;
    const int n0 = tg, n1 = tg + HALF_T;
    int k0 = off[n0], e0 = off[n0 + 1];
    int k1 = 0, e1 = 0;
    if (n1 < N_NODES) { k1 = off[n1]; e1 = off[n1 + 1]; }
    float deg0 = (float)(e0 - k0), deg1 = (float)(e1 - k1);
    float acc0[10], acc1[10];
#pragma unroll
    for (int q = 0; q < 10; ++q) { acc0[q] = 0.f; acc1[q] = 0.f; }

    bool coop = true;
    if (threadIdx.x == 0) {
        barrier_arrive(bar, blockIdx.x);
        coop = barrier_wait(bar, ENTRY_BUDGET);
    }
    __syncthreads();

    constexpr int PH = 8;   // 2 MB of h1 per phase
    for (int s = 0; s < PH; ++s) {
        const int lim = (s + 1) << (SLICE_SHIFT + 1);
        l2_scan_phase(k0, e0, lim, ssrc, h1, acc0);
        l2_scan_phase(k1, e1, lim, ssrc, h1, acc1);
        if (s < PH - 1) {
            if (threadIdx.x == 0) {
                int* rec = bar + (1 + s) * BAR_REC_INTS;
                barrier_arrive(rec, blockIdx.x);
                if (coop) coop = barrier_wait(rec, PHASE_BUDGET);
            }
            __syncthreads();
        }
    }
    l2_tail(n0, deg0, acc0, h1, s_wl, s_wr, s_b, h2);
    l2_tail(n1, deg1, acc1, h1, s_wl, s_wr, s_b, h2);
}

__device__ __forceinline__ void l3_tail(int n, float deg, float* acc,
        const int* __restrict__ h2, const float* s_wl, const float* s_wr,
        const float* s_b, const float* s_wc, const float* s_bc,
        float* __restrict__ out) {
    if (n >= N_NODES) return;
    float inv = 1.f / fmaxf(deg, 1.f);
#pragma unroll
    for (int q = 0; q < 20; ++q) acc[q] *= inv;
    float xv[20];
    {
        const int* row = h2 + (long)n * 16;
        int4 va = *(const int4*)row;
        int4 vb = *(const int4*)(row + 4);
        int2 vc = *(const int2*)(row + 8);
        float2 f;
        f = up2(va.x); xv[0] = f.x; xv[1] = f.y;
        f = up2(va.y); xv[2] = f.x; xv[3] = f.y;
        f = up2(va.z); xv[4] = f.x; xv[5] = f.y;
        f = up2(va.w); xv[6] = f.x; xv[7] = f.y;
        f = up2(vb.x); xv[8] = f.x; xv[9] = f.y;
        f = up2(vb.y); xv[10] = f.x; xv[11] = f.y;
        f = up2(vb.z); xv[12] = f.x; xv[13] = f.y;
        f = up2(vb.w); xv[14] = f.x; xv[15] = f.y;
        f = up2(vc.x); xv[16] = f.x; xv[17] = f.y;
        f = up2(vc.y); xv[18] = f.x; xv[19] = f.y;
    }
    float h3[20];
#pragma unroll
    for (int j = 0; j < 20; ++j) {
        float r = s_b[j];
#pragma unroll
        for (int kk = 0; kk < 20; ++kk)
            r += s_wl[j * 20 + kk] * acc[kk] + s_wr[j * 20 + kk] * xv[kk];
        h3[j] = fmaxf(r, 0.f);
    }
#pragma unroll
    for (int j = 0; j < 8; ++j) {
        float r = s_bc[j];
#pragma unroll
        for (int kk = 0; kk < 20; ++kk) r += s_wc[j * 20 + kk] * h3[kk];
        out[(long)n * 8 + j] = r;
    }
}

__global__ __launch_bounds__(256, 4) void fused_l3p(
        const int* __restrict__ off, const int* __restrict__ ssrc,
        const int* __restrict__ h2,
        const float* __restrict__ w3l, const float* __restrict__ b3,
        const float* __restrict__ w3r,
        const float* __restrict__ wc, const float* __restrict__ bc,
        float* __restrict__ out, int* __restrict__ bar) {
    __shared__ float s_wl[400];
    __shared__ float s_wr[400];
    __shared__ float s_b[20];
    __shared__ float s_wc[160];
    __shared__ float s_bc[8];
    for (int t = threadIdx.x; t < 400; t += 256) {
        s_wl[t] = w3l[t];
        s_wr[t] = w3r[t];
    }
    if (threadIdx.x < 160) s_wc[threadIdx.x] = wc[threadIdx.x];
    if (threadIdx.x >= 192 && threadIdx.x < 212) s_b[threadIdx.x - 192] = b3[threadIdx.x - 192];
    if (threadIdx.x >= 224 && threadIdx.x < 232) s_bc[threadIdx.x - 224] = bc[threadIdx.x - 224];
    __syncthreads();

    const int tg = blockIdx.x * 256 + threadIdx.x;
    const int n0 = tg, n1 = tg + HALF_T;
    int k0 = off[n0], e0 = off[n0 + 1];
    int k1 = 0, e1 = 0;
    if (n1 < N_NODES) { k1 = off[n1]; e1 = off[n1 + 1]; }
    float deg0 = (float)(e0 - k0), deg1 = (float)(e1 - k1);
    float acc0[20], acc1[20];
#pragma unroll
    for (int q = 0; q < 20; ++q) { acc0[q] = 0.f; acc1[q] = 0.f; }

    bool coop = true;
    if (threadIdx.x == 0) {
        barrier_arrive(bar, blockIdx.x);
        coop = barrier_wait(bar, ENTRY_BUDGET);
    }
    __syncthreads();

    constexpr int PH = 16;   // 2 MB of h2 per phase
    for (int s = 0; s < PH; ++s) {
        const int lim = (s + 1) << SLICE_SHIFT;
        l3_scan_phase(k0, e0, lim, ssrc, h2, acc0);
        l3_scan_phase(k1, e1, lim, ssrc, h2, acc1);
        if (s < PH - 1) {
            if (threadIdx.x == 0) {
                int* rec = bar + (1 + s) * BAR_REC_INTS;
                barrier_arrive(rec, blockIdx.x);
                if (coop) coop = barrier_wait(rec, PHASE_BUDGET);
            }
            __syncthreads();
        }
    }
    l3_tail(n0, deg0, acc0, h2, s_wl, s_wr, s_b, s_wc, s_bc, out);
    l3_tail(n1, deg1, acc1, h2, s_wl, s_wr, s_b, s_wc, s_bc, out);
}

// ============================================================================
// Path B (fallback, small ws): float-atomic version
// ============================================================================

__global__ void deg_kernel(const int* __restrict__ dst, int* __restrict__ deg) {
    int i = blockIdx.x * blockDim.x + threadIdx.x;
    if (i < N_EDGES) atomicAdd(&deg[dst[i]], 1);
}

template <int F>
__global__ void edge_agg(const int* __restrict__ src, const int* __restrict__ dst,
                         const float* __restrict__ h, float* __restrict__ agg) {
    int i = blockIdx.x * blockDim.x + threadIdx.x;
    if (i >= N_EDGES) return;
    int s = src[i];
    int d = dst[i];
    const float* hs = h + (long)s * F;
    float* ad = agg + (long)d * F;
#pragma unroll
    for (int f = 0; f < F; ++f) atomicAdd(&ad[f], hs[f]);
}

template <int FIN, int FOUT>
__global__ void node_apply(const float* __restrict__ agg, const float* __restrict__ hin,
                           const int* __restrict__ deg, const float* __restrict__ wl,
                           const float* __restrict__ bl, const float* __restrict__ wr,
                           float* __restrict__ hout) {
    __shared__ float s_wl[FOUT * FIN];
    __shared__ float s_wr[FOUT * FIN];
    __shared__ float s_b[FOUT];
    for (int t = threadIdx.x; t < FOUT * FIN; t += blockDim.x) {
        s_wl[t] = wl[t];
        s_wr[t] = wr[t];
    }
    for (int t = threadIdx.x; t < FOUT; t += blockDim.x) s_b[t] = bl[t];
    __syncthreads();
    int i = blockIdx.x * blockDim.x + threadIdx.x;
    if (i >= N_NODES) return;
    float inv = 1.0f / fmaxf((float)deg[i], 1.0f);
    float a[FIN], xv[FIN];
#pragma unroll
    for (int kk = 0; kk < FIN; ++kk) {
        a[kk] = agg[(long)i * FIN + kk] * inv;
        xv[kk] = hin[(long)i * FIN + kk];
    }
#pragma unroll
    for (int j = 0; j < FOUT; ++j) {
        float r = s_b[j];
#pragma unroll
        for (int kk = 0; kk < FIN; ++kk) r += s_wl[j * FIN + kk] * a[kk] + s_wr[j * FIN + kk] * xv[kk];
        hout[(long)i * FOUT + j] = fmaxf(r, 0.f);
    }
}

__global__ void node_final_old(const float* __restrict__ agg, const float* __restrict__ hin,
                               const int* __restrict__ deg, const float* __restrict__ w3l,
                               const float* __restrict__ b3, const float* __restrict__ w3r,
                               const float* __restrict__ wc, const float* __restrict__ bc,
                               float* __restrict__ out) {
    __shared__ float s_wl[400];
    __shared__ float s_wr[400];
    __shared__ float s_b[20];
    __shared__ float s_wc[160];
    __shared__ float s_bc[8];
    for (int t = threadIdx.x; t < 400; t += blockDim.x) {
        s_wl[t] = w3l[t];
        s_wr[t] = w3r[t];
    }
    for (int t = threadIdx.x; t < 160; t += blockDim.x) s_wc[t] = wc[t];
    for (int t = threadIdx.x; t < 20; t += blockDim.x) s_b[t] = b3[t];
    for (int t = threadIdx.x; t < 8; t += blockDim.x) s_bc[t] = bc[t];
    __syncthreads();
    int i = blockIdx.x * blockDim.x + threadIdx.x;
    if (i >= N_NODES) return;
    float inv = 1.0f / fmaxf((float)deg[i], 1.0f);
    float a[20], xv[20];
#pragma unroll
    for (int kk = 0; kk < 20; ++kk) {
        a[kk] = agg[(long)i * 20 + kk] * inv;
        xv[kk] = hin[(long)i * 20 + kk];
    }
    float h3[20];
#pragma unroll
    for (int j = 0; j < 20; ++j) {
        float r = s_b[j];
#pragma unroll
        for (int kk = 0; kk < 20; ++kk) r += s_wl[j * 20 + kk] * a[kk] + s_wr[j * 20 + kk] * xv[kk];
        h3[j] = fmaxf(r, 0.f);
    }
#pragma unroll
    for (int j = 0; j < 8; ++j) {
        float r = s_bc[j];
#pragma unroll
        for (int kk = 0; kk < 20; ++kk) r += s_wc[j * 20 + kk] * h3[kk];
        out[(long)i * 8 + j] = r;
    }
}

// ============================================================================

extern "C" void kernel_launch(void* const* d_in, const int* in_sizes, int n_in,
                              void* d_out, int out_size, void* d_ws, size_t ws_size,
                              hipStream_t stream) {
    const float* x = (const float*)d_in[0];
    const int* ei = (const int*)d_in[1];  // [2, E]: src row then dst row
    const float* w1l = (const float*)d_in[2];
    const float* b1 = (const float*)d_in[3];
    const float* w1r = (const float*)d_in[4];
    const float* w2l = (const float*)d_in[5];
    const float* b2 = (const float*)d_in[6];
    const float* w2r = (const float*)d_in[7];
    const float* w3l = (const float*)d_in[8];
    const float* b3 = (const float*)d_in[9];
    const float* w3r = (const float*)d_in[10];
    const float* wc = (const float*)d_in[11];
    const float* bc = (const float*)d_in[12];
    float* out = (float*)d_out;

    const int* src = ei;
    const int* dst = ei + N_EDGES;

    const int BT = 256;
    dim3 blk(BT);
    dim3 egrid((N_EDGES + BT - 1) / BT);
    dim3 ngrid(NB);

    // ---- Path A v7 layout (bytes):
    // off    [0,          2,000,128)   500001 ints (padded)
    // bbase  [2,000,128,  2,004,352)   1025 ints (padded)
    // gcur   [2,004,352,  2,008,448)   1024 ints
    // P      [2,008,448,  66,008,448)  16M packed ints (dead after fine_sort)
    //   xh   [2,008,448,  6,008,448)   overlay: 500K x 8 B fp16 rows
    //   h1   [6,008,448, 22,008,448)   overlay: 500K x 32 B fp16 rows
    //   h2   [22,008,448, 54,008,448)  overlay: 500K x 64 B fp16 rows
    //   bar  [54,008,448, 54,106,752)  overlay: 24 x 4 KB barrier records
    // S      [66,008,448, 130,008,448) 16M sorted src
    const size_t NEED_A = 130008448;

    if (ws_size >= NEED_A) {
        char* ws = (char*)d_ws;
        int* off = (int*)ws;
        int* bbase = (int*)(ws + 2000128);
        int* gcur = (int*)(ws + 2004352);
        int* P = (int*)(ws + 2008448);
        int2* xh = (int2*)(ws + 2008448);
        int* h1 = (int*)(ws + 6008448);
        int* h2 = (int*)(ws + 22008448);
        int* bar2 = (int*)(ws + 54008448);               // 8 records (entry + 7)
        int* bar3 = bar2 + 8 * BAR_REC_INTS;             // 16 records (entry + 15)
        int* S = (int*)(ws + 66008448);

        hipMemsetAsync(gcur, 0, NBUCK_PAD * sizeof(int), stream);
        bucket_hist<<<1024, blk, 0, stream>>>(dst, gcur);
        bucket_scan<<<1, blk, 0, stream>>>(gcur, bbase);
        bucket_scatter<<<NSB, blk, 0, stream>>>(src, dst, gcur, P);
        fine_sort<<<NBUCK, blk, 0, stream>>>(P, bbase, off, S);

        // P is dead after fine_sort; zero the barrier overlay (stream-ordered)
        hipMemsetAsync(bar2, 0, 24 * BAR_REC_INTS * sizeof(int), stream);

        convert_x<<<ngrid, blk, 0, stream>>>(x, xh);
        fused_l1<<<ngrid, blk, 0, stream>>>(off, S, xh, x, w1l, b1, w1r, h1);
        fused_l2p<<<GRID_BLK, blk, 0, stream>>>(off, S, h1, w2l, b2, w2r, h2, bar2);
        fused_l3p<<<GRID_BLK, blk, 0, stream>>>(off, S, h2, w3l, b3, w3r, wc, bc, out, bar3);
    } else {
        // fallback: float-atomic path (needs 102 MB)
        char* ws = (char*)d_ws;
        int* deg = (int*)ws;
        float* agg = (float*)(ws + 2000000);
        float* h1 = (float*)(ws + 42000000);
        float* h2 = (float*)(ws + 62000000);

        hipMemsetAsync(deg, 0, (size_t)N_NODES * sizeof(int), stream);
        deg_kernel<<<egrid, blk, 0, stream>>>(dst, deg);

        hipMemsetAsync(agg, 0, (size_t)N_NODES * 4 * sizeof(float), stream);
        edge_agg<4><<<egrid, blk, 0, stream>>>(src, dst, x, agg);
        node_apply<4, 10><<<ngrid, blk, 0, stream>>>(agg, x, deg, w1l, b1, w1r, h1);

        hipMemsetAsync(agg, 0, (size_t)N_NODES * 10 * sizeof(float), stream);
        edge_agg<10><<<egrid, blk, 0, stream>>>(src, dst, h1, agg);
        node_apply<10, 20><<<ngrid, blk, 0, stream>>>(agg, h1, deg, w2l, b2, w2r, h2);

        hipMemsetAsync(agg, 0, (size_t)N_NODES * 20 * sizeof(float), stream);
        edge_agg<20><<<egrid, blk, 0, stream>>>(src, dst, h2, agg);
        node_final_old<<<ngrid, blk, 0, stream>>>(agg, h2, deg, w3l, b3, w3r, wc, bc, out);
    }
}

// Round 4
// 1587.053 us; speedup vs baseline: 2.4331x; 1.0409x over previous
//
#include <hip/hip_runtime.h>
#include <hip/hip_fp16.h>

#define N_NODES 500000
#define N_EDGES 16000000
#define NB 1954          // ceil(N_NODES/256)
#define NPB_LOG 9
#define NPB 512          // nodes per bucket
#define NBUCK 977        // ceil(N_NODES/NPB)
#define NBUCK_PAD 1024
#define CH 32768         // edges per bucket_scatter block
#define NSB 489          // ceil(N_EDGES/CH)

// sub-sort of each node's neighbor list by src slice for L2 locality:
// src < 500000 < 2^19; src>>15 in [0,15] -> 16 slices of 32768 nodes.
#define SLICE_SHIFT 15
#define NSLICE 16
#define NKEY (NPB * NSLICE)   // 8192 counters = 32 KB LDS

// phased layer kernels: 1024 co-resident blocks (4/CU), 2 nodes per thread
#define GRID_BLK 1024
#define HALF_T (GRID_BLK * 256)   // 262144

// distributed two-level barrier: 16 sub-counters (128 B apart) + master + flag
#define BAR_SUBC 16
#define BAR_SUBQ (GRID_BLK / BAR_SUBC)   // 64 arrivals per sub-counter
#define BAR_REC_INTS 1024                // 4 KB per barrier record
#define BAR_MASTER 512
#define BAR_FLAG 544
#define ENTRY_BUDGET 1500
#define PHASE_BUDGET 400

// ---------- fp16 pack/unpack helpers (fp32 math everywhere else) ----------
__device__ __forceinline__ float2 up2(int p) {
    __half2 h = *reinterpret_cast<__half2*>(&p);
    return __half22float2(h);
}
__device__ __forceinline__ int pk2(float a, float b) {
    __half2 h = __floats2half2_rn(a, b);
    return *reinterpret_cast<int*>(&h);
}

// ---------- performance-only distributed barrier (bounded spin) ------------
__device__ __forceinline__ void barrier_arrive(int* rec, int bid) {
    int r = __hip_atomic_fetch_add(&rec[(bid & (BAR_SUBC - 1)) * 32], 1,
                                   __ATOMIC_RELAXED, __HIP_MEMORY_SCOPE_AGENT);
    if (r == BAR_SUBQ - 1) {
        int mr = __hip_atomic_fetch_add(&rec[BAR_MASTER], 1,
                                        __ATOMIC_RELAXED, __HIP_MEMORY_SCOPE_AGENT);
        if (mr == BAR_SUBC - 1)
            __hip_atomic_store(&rec[BAR_FLAG], 1,
                               __ATOMIC_RELAXED, __HIP_MEMORY_SCOPE_AGENT);
    }
}
__device__ __forceinline__ bool barrier_wait(int* rec, int budget) {
    int spins = 0;
    while (__hip_atomic_load(&rec[BAR_FLAG],
                             __ATOMIC_RELAXED, __HIP_MEMORY_SCOPE_AGENT) == 0) {
        if (++spins > budget) return false;
        __builtin_amdgcn_s_sleep(8);
    }
    return true;
}

// ============================================================================
// Two-level counting sort (LDS atomics) -> CSR (off, S)
// ============================================================================

__global__ void bucket_hist(const int* __restrict__ dst, int* __restrict__ ghist) {
    __shared__ int lhist[NBUCK_PAD];
    for (int t = threadIdx.x; t < NBUCK_PAD; t += 256) lhist[t] = 0;
    __syncthreads();
    int stride = gridDim.x * 256;
    for (int i = blockIdx.x * 256 + threadIdx.x; i < N_EDGES; i += stride) {
        atomicAdd(&lhist[dst[i] >> NPB_LOG], 1);
    }
    __syncthreads();
    for (int t = threadIdx.x; t < NBUCK_PAD; t += 256) {
        int c = lhist[t];
        if (c) atomicAdd(&ghist[t], c);
    }
}

__global__ void bucket_scan(int* __restrict__ gcur, int* __restrict__ bbase) {
    __shared__ int s[256];
    int t = threadIdx.x;
    int v[4], sum = 0, loc[4];
#pragma unroll
    for (int j = 0; j < 4; ++j) {
        v[j] = gcur[t * 4 + j];
        loc[j] = sum;
        sum += v[j];
    }
    s[t] = sum;
    __syncthreads();
    for (int o = 1; o < 256; o <<= 1) {
        int x = (t >= o) ? s[t - o] : 0;
        __syncthreads();
        s[t] += x;
        __syncthreads();
    }
    int excl = s[t] - sum;
#pragma unroll
    for (int j = 0; j < 4; ++j) {
        int e = excl + loc[j];
        bbase[t * 4 + j] = e;
        gcur[t * 4 + j] = e;
    }
    if (t == 255) bbase[NBUCK_PAD] = s[255];
}

__global__ void bucket_scatter(const int* __restrict__ src, const int* __restrict__ dst,
                               int* __restrict__ gcur, int* __restrict__ P) {
    __shared__ int lhist[NBUCK_PAD];
    __shared__ int lcur[NBUCK_PAD];
    for (int t = threadIdx.x; t < NBUCK_PAD; t += 256) lhist[t] = 0;
    __syncthreads();
    int e0 = blockIdx.x * CH;
    int e1 = min(e0 + CH, N_EDGES);
    for (int i = e0 + threadIdx.x; i < e1; i += 256) {
        atomicAdd(&lhist[dst[i] >> NPB_LOG], 1);
    }
    __syncthreads();
    for (int t = threadIdx.x; t < NBUCK_PAD; t += 256) {
        int c = lhist[t];
        lcur[t] = c ? atomicAdd(&gcur[t], c) : 0;
    }
    __syncthreads();
    for (int i = e0 + threadIdx.x; i < e1; i += 256) {
        int d = dst[i];
        int s = src[i];
        int b = d >> NPB_LOG;
        int pos = atomicAdd(&lcur[b], 1);
        P[pos] = ((d & (NPB - 1)) << 19) | s;
    }
}

// fine_sort: counting key = (node_in_bucket << 4) | (src >> 15).
// Per-node CSR segments, each node's neighbor list sub-ordered by src slice.
__global__ void fine_sort(const int* __restrict__ P, const int* __restrict__ bbase,
                          int* __restrict__ off, int* __restrict__ S) {
    __shared__ int hist[NKEY];   // 32 KB
    __shared__ int sscan[256];
    int t = threadIdx.x;
    int b = blockIdx.x;
    int bb = bbase[b];
    int be = bbase[b + 1];
    int node0 = b << NPB_LOG;

    for (int j = t; j < NKEY; j += 256) hist[j] = 0;
    __syncthreads();
    for (int j = bb + t; j < be; j += 256) {
        int p = P[j];
        int n = p >> 19;
        int s = p & 0x7FFFF;
        atomicAdd(&hist[(n << 4) | (s >> SLICE_SHIFT)], 1);
    }
    __syncthreads();

    // scan over 8192 counters: thread t owns keys [32t, 32t+32)
    int base = t * 32;
    int sum = 0;
#pragma unroll
    for (int j = 0; j < 32; ++j) sum += hist[base + j];
    sscan[t] = sum;
    __syncthreads();
    for (int o = 1; o < 256; o <<= 1) {
        int x = (t >= o) ? sscan[t - o] : 0;
        __syncthreads();
        sscan[t] += x;
        __syncthreads();
    }
    int run = sscan[t] - sum;
#pragma unroll
    for (int j = 0; j < 32; ++j) {
        int c = hist[base + j];
        hist[base + j] = run;
        run += c;
    }
    __syncthreads();

#pragma unroll
    for (int j = 0; j < 2; ++j) {
        int idx = t + j * 256;   // node_in_bucket
        int ng = node0 + idx;
        if (ng < N_NODES) off[ng] = bb + hist[idx << 4];
    }
    if (b == NBUCK - 1 && t == 0) off[N_NODES] = N_EDGES;
    __syncthreads();

    for (int j = bb + t; j < be; j += 256) {
        int p = P[j];
        int n = p >> 19;
        int s = p & 0x7FFFF;
        int pos = atomicAdd(&hist[(n << 4) | (s >> SLICE_SHIFT)], 1);
        S[bb + pos] = s;
    }
}

// count_slices: per node, pack the 16 per-slice counts as 16 u8 in an int4.
// Segment is already slice-sorted; counts are value-derived but this kernel
// is tiny (~30 us) and removes ALL value-dependence from the layer scans.
__global__ __launch_bounds__(256) void count_slices(const int* __restrict__ off,
        const int* __restrict__ S, int4* __restrict__ cnt8) {
    int i = blockIdx.x * 256 + threadIdx.x;
    if (i >= N_NODES) return;
    int b = off[i], e = off[i + 1];
    int w0 = 0, w1 = 0, w2 = 0, w3 = 0;
    for (int k = b; k < e; ++k) {
        int sl = S[k] >> SLICE_SHIFT;          // 0..15
        int inc = 1 << ((sl & 3) * 8);
        if (sl < 8) { if (sl < 4) w0 += inc; else w1 += inc; }
        else        { if (sl < 12) w2 += inc; else w3 += inc; }
    }
    cnt8[i] = make_int4(w0, w1, w2, w3);
}

// ============================================================================
// fp16 table prep: x (fp32, 4 feats) -> xh (fp16, 8 B rows)
// ============================================================================

__global__ void convert_x(const float* __restrict__ x, int2* __restrict__ xh) {
    int i = blockIdx.x * 256 + threadIdx.x;
    if (i >= N_NODES) return;
    float4 v = ((const float4*)x)[i];
    int2 r;
    r.x = pk2(v.x, v.y);
    r.y = pk2(v.z, v.w);
    xh[i] = r;
}

// ============================================================================
// Layer 1 (unphased): xh table is 4 MB ~ fits one XCD L2
// ============================================================================

__global__ __launch_bounds__(256, 4) void fused_l1(
        const int* __restrict__ off, const int* __restrict__ ssrc,
        const int2* __restrict__ xh, const float* __restrict__ x,
        const float* __restrict__ wl, const float* __restrict__ bl,
        const float* __restrict__ wr, int* __restrict__ h1) {
    __shared__ float s_wl[40];
    __shared__ float s_wr[40];
    __shared__ float s_b[10];
    if (threadIdx.x < 40) {
        s_wl[threadIdx.x] = wl[threadIdx.x];
        s_wr[threadIdx.x] = wr[threadIdx.x];
    }
    if (threadIdx.x >= 64 && threadIdx.x < 74) s_b[threadIdx.x - 64] = bl[threadIdx.x - 64];
    __syncthreads();

    int i = blockIdx.x * 256 + threadIdx.x;
    if (i >= N_NODES) return;

    int b = off[i], e = off[i + 1];
    constexpr int UN = 8;

    float acc[4] = {0.f, 0.f, 0.f, 0.f};

    int k = b;
    for (; k + UN - 1 < e; k += UN) {
        int sidx[UN];
#pragma unroll
        for (int u = 0; u < UN; ++u) sidx[u] = ssrc[k + u];
        int2 v[UN];
#pragma unroll
        for (int u = 0; u < UN; ++u) v[u] = xh[sidx[u]];
#pragma unroll
        for (int u = 0; u < UN; ++u) {
            float2 f0 = up2(v[u].x), f1 = up2(v[u].y);
            acc[0] += f0.x; acc[1] += f0.y; acc[2] += f1.x; acc[3] += f1.y;
        }
    }
    for (; k < e; ++k) {
        int2 v = xh[ssrc[k]];
        float2 f0 = up2(v.x), f1 = up2(v.y);
        acc[0] += f0.x; acc[1] += f0.y; acc[2] += f1.x; acc[3] += f1.y;
    }

    float inv = 1.f / fmaxf((float)(e - b), 1.f);
#pragma unroll
    for (int q = 0; q < 4; ++q) acc[q] *= inv;

    float4 xs = ((const float4*)x)[i];
    float xv[4] = {xs.x, xs.y, xs.z, xs.w};

    float r[10];
#pragma unroll
    for (int j = 0; j < 10; ++j) {
        float t = s_b[j];
#pragma unroll
        for (int kk = 0; kk < 4; ++kk) {
            t += s_wl[j * 4 + kk] * acc[kk] + s_wr[j * 4 + kk] * xv[kk];
        }
        r[j] = fmaxf(t, 0.f);
    }
    int4 o0;
    o0.x = pk2(r[0], r[1]); o0.y = pk2(r[2], r[3]);
    o0.z = pk2(r[4], r[5]); o0.w = pk2(r[6], r[7]);
    *(int4*)(h1 + (long)i * 8) = o0;
    h1[(long)i * 8 + 4] = pk2(r[8], r[9]);
}

// ============================================================================
// Phased layers 2 & 3: count-driven, value-independent batched scans
// ============================================================================

__device__ __forceinline__ void l2_scan_m(int& k, int m,
        const int* __restrict__ ssrc, const int* __restrict__ h1, float* acc) {
    for (; m >= 4; m -= 4, k += 4) {
        int sidx[4];
#pragma unroll
        for (int u = 0; u < 4; ++u) sidx[u] = ssrc[k + u];
        int4 v4[4];
        int v1[4];
#pragma unroll
        for (int u = 0; u < 4; ++u) {
            const int* row = h1 + (long)sidx[u] * 8;
            v4[u] = *(const int4*)row;
            v1[u] = row[4];
        }
#pragma unroll
        for (int u = 0; u < 4; ++u) {
            float2 f0 = up2(v4[u].x), f1 = up2(v4[u].y), f2 = up2(v4[u].z),
                   f3 = up2(v4[u].w), f4 = up2(v1[u]);
            acc[0] += f0.x; acc[1] += f0.y; acc[2] += f1.x; acc[3] += f1.y;
            acc[4] += f2.x; acc[5] += f2.y; acc[6] += f3.x; acc[7] += f3.y;
            acc[8] += f4.x; acc[9] += f4.y;
        }
    }
    for (; m > 0; --m, ++k) {
        const int* row = h1 + (long)ssrc[k] * 8;
        int4 v4 = *(const int4*)row;
        int v1 = row[4];
        float2 f0 = up2(v4.x), f1 = up2(v4.y), f2 = up2(v4.z), f3 = up2(v4.w), f4 = up2(v1);
        acc[0] += f0.x; acc[1] += f0.y; acc[2] += f1.x; acc[3] += f1.y;
        acc[4] += f2.x; acc[5] += f2.y; acc[6] += f3.x; acc[7] += f3.y;
        acc[8] += f4.x; acc[9] += f4.y;
    }
}

__device__ __forceinline__ void l3_scan_m(int& k, int m,
        const int* __restrict__ ssrc, const int* __restrict__ h2, float* acc) {
    for (; m >= 4; m -= 4, k += 4) {
        int sidx[4];
#pragma unroll
        for (int u = 0; u < 4; ++u) sidx[u] = ssrc[k + u];
        int4 va[4], vb[4];
        int2 vc[4];
#pragma unroll
        for (int u = 0; u < 4; ++u) {
            const int* row = h2 + (long)sidx[u] * 16;
            va[u] = *(const int4*)row;
            vb[u] = *(const int4*)(row + 4);
            vc[u] = *(const int2*)(row + 8);
        }
#pragma unroll
        for (int u = 0; u < 4; ++u) {
            float2 f;
            f = up2(va[u].x); acc[0] += f.x; acc[1] += f.y;
            f = up2(va[u].y); acc[2] += f.x; acc[3] += f.y;
            f = up2(va[u].z); acc[4] += f.x; acc[5] += f.y;
            f = up2(va[u].w); acc[6] += f.x; acc[7] += f.y;
            f = up2(vb[u].x); acc[8] += f.x; acc[9] += f.y;
            f = up2(vb[u].y); acc[10] += f.x; acc[11] += f.y;
            f = up2(vb[u].z); acc[12] += f.x; acc[13] += f.y;
            f = up2(vb[u].w); acc[14] += f.x; acc[15] += f.y;
            f = up2(vc[u].x); acc[16] += f.x; acc[17] += f.y;
            f = up2(vc[u].y); acc[18] += f.x; acc[19] += f.y;
        }
    }
    for (; m > 0; --m, ++k) {
        const int* row = h2 + (long)ssrc[k] * 16;
        int4 va = *(const int4*)row;
        int4 vb = *(const int4*)(row + 4);
        int2 vc = *(const int2*)(row + 8);
        float2 f;
        f = up2(va.x); acc[0] += f.x; acc[1] += f.y;
        f = up2(va.y); acc[2] += f.x; acc[3] += f.y;
        f = up2(va.z); acc[4] += f.x; acc[5] += f.y;
        f = up2(va.w); acc[6] += f.x; acc[7] += f.y;
        f = up2(vb.x); acc[8] += f.x; acc[9] += f.y;
        f = up2(vb.y); acc[10] += f.x; acc[11] += f.y;
        f = up2(vb.z); acc[12] += f.x; acc[13] += f.y;
        f = up2(vb.w); acc[14] += f.x; acc[15] += f.y;
        f = up2(vc.x); acc[16] += f.x; acc[17] += f.y;
        f = up2(vc.y); acc[18] += f.x; acc[19] += f.y;
    }
}

__device__ __forceinline__ void l2_tail(int n, float deg, float* acc,
        const int* __restrict__ h1, const float* s_wl, const float* s_wr,
        const float* s_b, int* __restrict__ h2) {
    if (n >= N_NODES) return;
    float inv = 1.f / fmaxf(deg, 1.f);
#pragma unroll
    for (int q = 0; q < 10; ++q) acc[q] *= inv;
    float xv[10];
    {
        const int* row = h1 + (long)n * 8;
        int4 v4 = *(const int4*)row;
        int v1 = row[4];
        float2 f0 = up2(v4.x), f1 = up2(v4.y), f2 = up2(v4.z), f3 = up2(v4.w), f4 = up2(v1);
        xv[0] = f0.x; xv[1] = f0.y; xv[2] = f1.x; xv[3] = f1.y;
        xv[4] = f2.x; xv[5] = f2.y; xv[6] = f3.x; xv[7] = f3.y;
        xv[8] = f4.x; xv[9] = f4.y;
    }
    float r[20];
#pragma unroll
    for (int j = 0; j < 20; ++j) {
        float t = s_b[j];
#pragma unroll
        for (int kk = 0; kk < 10; ++kk)
            t += s_wl[j * 10 + kk] * acc[kk] + s_wr[j * 10 + kk] * xv[kk];
        r[j] = fmaxf(t, 0.f);
    }
    int* o = h2 + (long)n * 16;
    int4 o0, o1;
    o0.x = pk2(r[0], r[1]);   o0.y = pk2(r[2], r[3]);
    o0.z = pk2(r[4], r[5]);   o0.w = pk2(r[6], r[7]);
    o1.x = pk2(r[8], r[9]);   o1.y = pk2(r[10], r[11]);
    o1.z = pk2(r[12], r[13]); o1.w = pk2(r[14], r[15]);
    *(int4*)o = o0;
    *(int4*)(o + 4) = o1;
    int2 o2;
    o2.x = pk2(r[16], r[17]); o2.y = pk2(r[18], r[19]);
    *(int2*)(o + 8) = o2;
}

__global__ __launch_bounds__(256, 4) void fused_l2p(
        const int* __restrict__ off, const int* __restrict__ ssrc,
        const int* __restrict__ h1,
        const float* __restrict__ wl, const float* __restrict__ bl,
        const float* __restrict__ wr, int* __restrict__ h2,
        const int4* __restrict__ cnt8, int* __restrict__ bar) {
    __shared__ float s_wl[200];
    __shared__ float s_wr[200];
    __shared__ float s_b[20];
    if (threadIdx.x < 200) {
        s_wl[threadIdx.x] = wl[threadIdx.x];
        s_wr[threadIdx.x] = wr[threadIdx.x];
    }
    if (threadIdx.x >= 224 && threadIdx.x < 244) s_b[threadIdx.x - 224] = bl[threadIdx.x - 224];
    __syncthreads();

    const int tg = blockIdx.x * 256 + threadIdx.x;
    const int n0 = tg, n1 = tg + HALF_T;
    int k0 = off[n0];
    float deg0 = (float)(off[n0 + 1] - k0);
    int4 c0 = cnt8[n0];
    int k1 = 0;
    float deg1 = 0.f;
    int4 c1 = make_int4(0, 0, 0, 0);
    if (n1 < N_NODES) {
        k1 = off[n1];
        deg1 = (float)(off[n1 + 1] - k1);
        c1 = cnt8[n1];
    }
    float acc0[10], acc1[10];
#pragma unroll
    for (int q = 0; q < 10; ++q) { acc0[q] = 0.f; acc1[q] = 0.f; }

    bool coop = true;
    if (threadIdx.x == 0) {
        barrier_arrive(bar, blockIdx.x);
        coop = barrier_wait(bar, ENTRY_BUDGET);
    }
    __syncthreads();

    constexpr int PH = 8;   // 2 MB of h1 per phase (2 slices)
    for (int s = 0; s < PH; ++s) {
        int cw0 = (s < 4) ? ((s < 2) ? c0.x : c0.y) : ((s < 6) ? c0.z : c0.w);
        int cw1 = (s < 4) ? ((s < 2) ? c1.x : c1.y) : ((s < 6) ? c1.z : c1.w);
        int sh = (s & 1) * 16;
        int m0 = ((cw0 >> sh) & 255) + ((cw0 >> (sh + 8)) & 255);
        int m1 = ((cw1 >> sh) & 255) + ((cw1 >> (sh + 8)) & 255);
        l2_scan_m(k0, m0, ssrc, h1, acc0);
        l2_scan_m(k1, m1, ssrc, h1, acc1);
        if (s < PH - 1) {
            if (threadIdx.x == 0) {
                int* rec = bar + (1 + s) * BAR_REC_INTS;
                barrier_arrive(rec, blockIdx.x);
                if (coop) coop = barrier_wait(rec, PHASE_BUDGET);
            }
            __syncthreads();
        }
    }
    l2_tail(n0, deg0, acc0, h1, s_wl, s_wr, s_b, h2);
    l2_tail(n1, deg1, acc1, h1, s_wl, s_wr, s_b, h2);
}

__device__ __forceinline__ void l3_tail(int n, float deg, float* acc,
        const int* __restrict__ h2, const float* s_wl, const float* s_wr,
        const float* s_b, const float* s_wc, const float* s_bc,
        float* __restrict__ out) {
    if (n >= N_NODES) return;
    float inv = 1.f / fmaxf(deg, 1.f);
#pragma unroll
    for (int q = 0; q < 20; ++q) acc[q] *= inv;
    float xv[20];
    {
        const int* row = h2 + (long)n * 16;
        int4 va = *(const int4*)row;
        int4 vb = *(const int4*)(row + 4);
        int2 vc = *(const int2*)(row + 8);
        float2 f;
        f = up2(va.x); xv[0] = f.x; xv[1] = f.y;
        f = up2(va.y); xv[2] = f.x; xv[3] = f.y;
        f = up2(va.z); xv[4] = f.x; xv[5] = f.y;
        f = up2(va.w); xv[6] = f.x; xv[7] = f.y;
        f = up2(vb.x); xv[8] = f.x; xv[9] = f.y;
        f = up2(vb.y); xv[10] = f.x; xv[11] = f.y;
        f = up2(vb.z); xv[12] = f.x; xv[13] = f.y;
        f = up2(vb.w); xv[14] = f.x; xv[15] = f.y;
        f = up2(vc.x); xv[16] = f.x; xv[17] = f.y;
        f = up2(vc.y); xv[18] = f.x; xv[19] = f.y;
    }
    float h3[20];
#pragma unroll
    for (int j = 0; j < 20; ++j) {
        float r = s_b[j];
#pragma unroll
        for (int kk = 0; kk < 20; ++kk)
            r += s_wl[j * 20 + kk] * acc[kk] + s_wr[j * 20 + kk] * xv[kk];
        h3[j] = fmaxf(r, 0.f);
    }
#pragma unroll
    for (int j = 0; j < 8; ++j) {
        float r = s_bc[j];
#pragma unroll
        for (int kk = 0; kk < 20; ++kk) r += s_wc[j * 20 + kk] * h3[kk];
        out[(long)n * 8 + j] = r;
    }
}

__global__ __launch_bounds__(256, 4) void fused_l3p(
        const int* __restrict__ off, const int* __restrict__ ssrc,
        const int* __restrict__ h2,
        const float* __restrict__ w3l, const float* __restrict__ b3,
        const float* __restrict__ w3r,
        const float* __restrict__ wc, const float* __restrict__ bc,
        float* __restrict__ out, const int4* __restrict__ cnt8,
        int* __restrict__ bar) {
    __shared__ float s_wl[400];
    __shared__ float s_wr[400];
    __shared__ float s_b[20];
    __shared__ float s_wc[160];
    __shared__ float s_bc[8];
    for (int t = threadIdx.x; t < 400; t += 256) {
        s_wl[t] = w3l[t];
        s_wr[t] = w3r[t];
    }
    if (threadIdx.x < 160) s_wc[threadIdx.x] = wc[threadIdx.x];
    if (threadIdx.x >= 192 && threadIdx.x < 212) s_b[threadIdx.x - 192] = b3[threadIdx.x - 192];
    if (threadIdx.x >= 224 && threadIdx.x < 232) s_bc[threadIdx.x - 224] = bc[threadIdx.x - 224];
    __syncthreads();

    const int tg = blockIdx.x * 256 + threadIdx.x;
    const int n0 = tg, n1 = tg + HALF_T;
    int k0 = off[n0];
    float deg0 = (float)(off[n0 + 1] - k0);
    int4 c0 = cnt8[n0];
    int k1 = 0;
    float deg1 = 0.f;
    int4 c1 = make_int4(0, 0, 0, 0);
    if (n1 < N_NODES) {
        k1 = off[n1];
        deg1 = (float)(off[n1 + 1] - k1);
        c1 = cnt8[n1];
    }
    float acc0[20], acc1[20];
#pragma unroll
    for (int q = 0; q < 20; ++q) { acc0[q] = 0.f; acc1[q] = 0.f; }

    bool coop = true;
    if (threadIdx.x == 0) {
        barrier_arrive(bar, blockIdx.x);
        coop = barrier_wait(bar, ENTRY_BUDGET);
    }
    __syncthreads();

    constexpr int PH = 16;   // 2 MB of h2 per phase (1 slice)
    for (int s = 0; s < PH; ++s) {
        int cw0 = (s < 8) ? ((s < 4) ? c0.x : c0.y) : ((s < 12) ? c0.z : c0.w);
        int cw1 = (s < 8) ? ((s < 4) ? c1.x : c1.y) : ((s < 12) ? c1.z : c1.w);
        int sh = (s & 3) * 8;
        int m0 = (cw0 >> sh) & 255;
        int m1 = (cw1 >> sh) & 255;
        l3_scan_m(k0, m0, ssrc, h2, acc0);
        l3_scan_m(k1, m1, ssrc, h2, acc1);
        if (s < PH - 1) {
            if (threadIdx.x == 0) {
                int* rec = bar + (1 + s) * BAR_REC_INTS;
                barrier_arrive(rec, blockIdx.x);
                if (coop) coop = barrier_wait(rec, PHASE_BUDGET);
            }
            __syncthreads();
        }
    }
    l3_tail(n0, deg0, acc0, h2, s_wl, s_wr, s_b, s_wc, s_bc, out);
    l3_tail(n1, deg1, acc1, h2, s_wl, s_wr, s_b, s_wc, s_bc, out);
}

// ============================================================================
// Path B (fallback, small ws): float-atomic version
// ============================================================================

__global__ void deg_kernel(const int* __restrict__ dst, int* __restrict__ deg) {
    int i = blockIdx.x * blockDim.x + threadIdx.x;
    if (i < N_EDGES) atomicAdd(&deg[dst[i]], 1);
}

template <int F>
__global__ void edge_agg(const int* __restrict__ src, const int* __restrict__ dst,
                         const float* __restrict__ h, float* __restrict__ agg) {
    int i = blockIdx.x * blockDim.x + threadIdx.x;
    if (i >= N_EDGES) return;
    int s = src[i];
    int d = dst[i];
    const float* hs = h + (long)s * F;
    float* ad = agg + (long)d * F;
#pragma unroll
    for (int f = 0; f < F; ++f) atomicAdd(&ad[f], hs[f]);
}

template <int FIN, int FOUT>
__global__ void node_apply(const float* __restrict__ agg, const float* __restrict__ hin,
                           const int* __restrict__ deg, const float* __restrict__ wl,
                           const float* __restrict__ bl, const float* __restrict__ wr,
                           float* __restrict__ hout) {
    __shared__ float s_wl[FOUT * FIN];
    __shared__ float s_wr[FOUT * FIN];
    __shared__ float s_b[FOUT];
    for (int t = threadIdx.x; t < FOUT * FIN; t += blockDim.x) {
        s_wl[t] = wl[t];
        s_wr[t] = wr[t];
    }
    for (int t = threadIdx.x; t < FOUT; t += blockDim.x) s_b[t] = bl[t];
    __syncthreads();
    int i = blockIdx.x * blockDim.x + threadIdx.x;
    if (i >= N_NODES) return;
    float inv = 1.0f / fmaxf((float)deg[i], 1.0f);
    float a[FIN], xv[FIN];
#pragma unroll
    for (int kk = 0; kk < FIN; ++kk) {
        a[kk] = agg[(long)i * FIN + kk] * inv;
        xv[kk] = hin[(long)i * FIN + kk];
    }
#pragma unroll
    for (int j = 0; j < FOUT; ++j) {
        float r = s_b[j];
#pragma unroll
        for (int kk = 0; kk < FIN; ++kk) r += s_wl[j * FIN + kk] * a[kk] + s_wr[j * FIN + kk] * xv[kk];
        hout[(long)i * FOUT + j] = fmaxf(r, 0.f);
    }
}

__global__ void node_final_old(const float* __restrict__ agg, const float* __restrict__ hin,
                               const int* __restrict__ deg, const float* __restrict__ w3l,
                               const float* __restrict__ b3, const float* __restrict__ w3r,
                               const float* __restrict__ wc, const float* __restrict__ bc,
                               float* __restrict__ out) {
    __shared__ float s_wl[400];
    __shared__ float s_wr[400];
    __shared__ float s_b[20];
    __shared__ float s_wc[160];
    __shared__ float s_bc[8];
    for (int t = threadIdx.x; t < 400; t += blockDim.x) {
        s_wl[t] = w3l[t];
        s_wr[t] = w3r[t];
    }
    for (int t = threadIdx.x; t < 160; t += blockDim.x) s_wc[t] = wc[t];
    for (int t = threadIdx.x; t < 20; t += blockDim.x) s_b[t] = b3[t];
    for (int t = threadIdx.x; t < 8; t += blockDim.x) s_bc[t] = bc[t];
    __syncthreads();
    int i = blockIdx.x * blockDim.x + threadIdx.x;
    if (i >= N_NODES) return;
    float inv = 1.0f / fmaxf((float)deg[i], 1.0f);
    float a[20], xv[20];
#pragma unroll
    for (int kk = 0; kk < 20; ++kk) {
        a[kk] = agg[(long)i * 20 + kk] * inv;
        xv[kk] = hin[(long)i * 20 + kk];
    }
    float h3[20];
#pragma unroll
    for (int j = 0; j < 20; ++j) {
        float r = s_b[j];
#pragma unroll
        for (int kk = 0; kk < 20; ++kk) r += s_wl[j * 20 + kk] * a[kk] + s_wr[j * 20 + kk] * xv[kk];
        h3[j] = fmaxf(r, 0.f);
    }
#pragma unroll
    for (int j = 0; j < 8; ++j) {
        float r = s_bc[j];
#pragma unroll
        for (int kk = 0; kk < 20; ++kk) r += s_wc[j * 20 + kk] * h3[kk];
        out[(long)i * 8 + j] = r;
    }
}

// ============================================================================

extern "C" void kernel_launch(void* const* d_in, const int* in_sizes, int n_in,
                              void* d_out, int out_size, void* d_ws, size_t ws_size,
                              hipStream_t stream) {
    const float* x = (const float*)d_in[0];
    const int* ei = (const int*)d_in[1];  // [2, E]: src row then dst row
    const float* w1l = (const float*)d_in[2];
    const float* b1 = (const float*)d_in[3];
    const float* w1r = (const float*)d_in[4];
    const float* w2l = (const float*)d_in[5];
    const float* b2 = (const float*)d_in[6];
    const float* w2r = (const float*)d_in[7];
    const float* w3l = (const float*)d_in[8];
    const float* b3 = (const float*)d_in[9];
    const float* w3r = (const float*)d_in[10];
    const float* wc = (const float*)d_in[11];
    const float* bc = (const float*)d_in[12];
    float* out = (float*)d_out;

    const int* src = ei;
    const int* dst = ei + N_EDGES;

    const int BT = 256;
    dim3 blk(BT);
    dim3 egrid((N_EDGES + BT - 1) / BT);
    dim3 ngrid(NB);

    // ---- Path A v8 layout (bytes):
    // off    [0,          2,000,128)   500001 ints (padded)
    // bbase  [2,000,128,  2,004,352)   1025 ints (padded)
    // gcur   [2,004,352,  2,008,448)   1024 ints
    // P      [2,008,448,  66,008,448)  16M packed ints (dead after fine_sort)
    //   xh   [2,008,448,  6,008,448)   overlay: 500K x 8 B fp16 rows
    //   h1   [6,008,448, 22,008,448)   overlay: 500K x 32 B fp16 rows
    //   h2   [22,008,448, 54,008,448)  overlay: 500K x 64 B fp16 rows
    //   bar  [54,008,448, 54,106,752)  overlay: 24 x 4 KB barrier records
    //   cnt8 [54,206,464, 62,206,464)  overlay: 500K x 16 B slice counts
    // S      [66,008,448, 130,008,448) 16M sorted src
    const size_t NEED_A = 130008448;

    if (ws_size >= NEED_A) {
        char* ws = (char*)d_ws;
        int* off = (int*)ws;
        int* bbase = (int*)(ws + 2000128);
        int* gcur = (int*)(ws + 2004352);
        int* P = (int*)(ws + 2008448);
        int2* xh = (int2*)(ws + 2008448);
        int* h1 = (int*)(ws + 6008448);
        int* h2 = (int*)(ws + 22008448);
        int* bar2 = (int*)(ws + 54008448);               // 8 records (entry + 7)
        int* bar3 = bar2 + 8 * BAR_REC_INTS;             // 16 records (entry + 15)
        int4* cnt8 = (int4*)(ws + 54206464);
        int* S = (int*)(ws + 66008448);

        hipMemsetAsync(gcur, 0, NBUCK_PAD * sizeof(int), stream);
        bucket_hist<<<1024, blk, 0, stream>>>(dst, gcur);
        bucket_scan<<<1, blk, 0, stream>>>(gcur, bbase);
        bucket_scatter<<<NSB, blk, 0, stream>>>(src, dst, gcur, P);
        fine_sort<<<NBUCK, blk, 0, stream>>>(P, bbase, off, S);

        // P is dead after fine_sort; zero the barrier overlay (stream-ordered)
        hipMemsetAsync(bar2, 0, 24 * BAR_REC_INTS * sizeof(int), stream);

        count_slices<<<ngrid, blk, 0, stream>>>(off, S, cnt8);
        convert_x<<<ngrid, blk, 0, stream>>>(x, xh);
        fused_l1<<<ngrid, blk, 0, stream>>>(off, S, xh, x, w1l, b1, w1r, h1);
        fused_l2p<<<GRID_BLK, blk, 0, stream>>>(off, S, h1, w2l, b2, w2r, h2, cnt8, bar2);
        fused_l3p<<<GRID_BLK, blk, 0, stream>>>(off, S, h2, w3l, b3, w3r, wc, bc, out, cnt8, bar3);
    } else {
        // fallback: float-atomic path (needs 102 MB)
        char* ws = (char*)d_ws;
        int* deg = (int*)ws;
        float* agg = (float*)(ws + 2000000);
        float* h1 = (float*)(ws + 42000000);
        float* h2 = (float*)(ws + 62000000);

        hipMemsetAsync(deg, 0, (size_t)N_NODES * sizeof(int), stream);
        deg_kernel<<<egrid, blk, 0, stream>>>(dst, deg);

        hipMemsetAsync(agg, 0, (size_t)N_NODES * 4 * sizeof(float), stream);
        edge_agg<4><<<egrid, blk, 0, stream>>>(src, dst, x, agg);
        node_apply<4, 10><<<ngrid, blk, 0, stream>>>(agg, x, deg, w1l, b1, w1r, h1);

        hipMemsetAsync(agg, 0, (size_t)N_NODES * 10 * sizeof(float), stream);
        edge_agg<10><<<egrid, blk, 0, stream>>>(src, dst, h1, agg);
        node_apply<10, 20><<<ngrid, blk, 0, stream>>>(agg, h1, deg, w2l, b2, w2r, h2);

        hipMemsetAsync(agg, 0, (size_t)N_NODES * 20 * sizeof(float), stream);
        edge_agg<20><<<egrid, blk, 0, stream>>>(src, dst, h2, agg);
        node_final_old<<<ngrid, blk, 0, stream>>>(agg, h2, deg, w3l, b3, w3r, wc, bc, out);
    }
}

// Round 5
// 1494.313 us; speedup vs baseline: 2.5841x; 1.0621x over previous
//
#include <hip/hip_runtime.h>
#include <hip/hip_fp16.h>

#define N_NODES 500000
#define N_EDGES 16000000
#define NB 1954          // ceil(N_NODES/256)
#define NPB_LOG 9
#define NPB 512          // nodes per bucket
#define NBUCK 977        // ceil(N_NODES/NPB)
#define NBUCK_PAD 1024
#define CH 16384         // edges per bucket_scatter block (LDS-staged)
#define NSB 977          // ceil(N_EDGES/CH)

// sub-sort of each node's neighbor list by src slice for L2 locality:
// src < 500000 < 2^19; src>>15 in [0,15] -> 16 slices of 32768 nodes.
#define SLICE_SHIFT 15
#define NSLICE 16
#define NKEY (NPB * NSLICE)   // 8192 counters = 32 KB LDS

// phased layer kernels: 1024 co-resident blocks (4/CU), 2 nodes per thread
#define GRID_BLK 1024
#define HALF_T (GRID_BLK * 256)   // 262144

// distributed two-level barrier: 16 sub-counters (128 B apart) + master + flag
#define BAR_SUBC 16
#define BAR_SUBQ (GRID_BLK / BAR_SUBC)   // 64 arrivals per sub-counter
#define BAR_REC_INTS 1024                // 4 KB per barrier record
#define BAR_MASTER 512
#define BAR_FLAG 544
#define ENTRY_BUDGET 1500
#define PHASE_BUDGET 400

// ---------- fp16 pack/unpack helpers (fp32 math everywhere else) ----------
__device__ __forceinline__ float2 up2(int p) {
    __half2 h = *reinterpret_cast<__half2*>(&p);
    return __half22float2(h);
}
__device__ __forceinline__ int pk2(float a, float b) {
    __half2 h = __floats2half2_rn(a, b);
    return *reinterpret_cast<int*>(&h);
}

// ---------- performance-only distributed barrier (bounded spin) ------------
__device__ __forceinline__ void barrier_arrive(int* rec, int bid) {
    int r = __hip_atomic_fetch_add(&rec[(bid & (BAR_SUBC - 1)) * 32], 1,
                                   __ATOMIC_RELAXED, __HIP_MEMORY_SCOPE_AGENT);
    if (r == BAR_SUBQ - 1) {
        int mr = __hip_atomic_fetch_add(&rec[BAR_MASTER], 1,
                                        __ATOMIC_RELAXED, __HIP_MEMORY_SCOPE_AGENT);
        if (mr == BAR_SUBC - 1)
            __hip_atomic_store(&rec[BAR_FLAG], 1,
                               __ATOMIC_RELAXED, __HIP_MEMORY_SCOPE_AGENT);
    }
}
__device__ __forceinline__ bool barrier_wait(int* rec, int budget) {
    int spins = 0;
    while (__hip_atomic_load(&rec[BAR_FLAG],
                             __ATOMIC_RELAXED, __HIP_MEMORY_SCOPE_AGENT) == 0) {
        if (++spins > budget) return false;
        __builtin_amdgcn_s_sleep(8);
    }
    return true;
}

// ============================================================================
// Two-level counting sort (LDS atomics) -> CSR (off, S)
// ============================================================================

__global__ void bucket_hist(const int* __restrict__ dst, int* __restrict__ ghist) {
    __shared__ int lhist[NBUCK_PAD];
    for (int t = threadIdx.x; t < NBUCK_PAD; t += 256) lhist[t] = 0;
    __syncthreads();
    int stride = gridDim.x * 256;
    for (int i = blockIdx.x * 256 + threadIdx.x; i < N_EDGES; i += stride) {
        atomicAdd(&lhist[dst[i] >> NPB_LOG], 1);
    }
    __syncthreads();
    for (int t = threadIdx.x; t < NBUCK_PAD; t += 256) {
        int c = lhist[t];
        if (c) atomicAdd(&ghist[t], c);
    }
}

__global__ void bucket_scan(int* __restrict__ gcur, int* __restrict__ bbase) {
    __shared__ int s[256];
    int t = threadIdx.x;
    int v[4], sum = 0, loc[4];
#pragma unroll
    for (int j = 0; j < 4; ++j) {
        v[j] = gcur[t * 4 + j];
        loc[j] = sum;
        sum += v[j];
    }
    s[t] = sum;
    __syncthreads();
    for (int o = 1; o < 256; o <<= 1) {
        int x = (t >= o) ? s[t - o] : 0;
        __syncthreads();
        s[t] += x;
        __syncthreads();
    }
    int excl = s[t] - sum;
#pragma unroll
    for (int j = 0; j < 4; ++j) {
        int e = excl + loc[j];
        bbase[t * 4 + j] = e;
        gcur[t * 4 + j] = e;
    }
    if (t == 255) bbase[NBUCK_PAD] = s[255];
}

// bucket_scatter v2: LDS-staged local sort -> coalesced global run writes.
// Fixes round-4's 6.4x write amplification (408 MB for a 64 MB payload).
__global__ __launch_bounds__(256) void bucket_scatter(
        const int* __restrict__ src, const int* __restrict__ dst,
        int* __restrict__ gcur, int* __restrict__ P) {
    __shared__ int lP[CH];             // 64 KB staged packed values
    __shared__ int lhist[NBUCK_PAD];   // counts -> local cursor
    __shared__ int lexcl[NBUCK_PAD];   // local exclusive prefix
    __shared__ int gbase[NBUCK_PAD];   // global base per bucket
    __shared__ int sscan[256];
    int t = threadIdx.x;
    for (int j = t; j < NBUCK_PAD; j += 256) lhist[j] = 0;
    __syncthreads();

    int e0 = blockIdx.x * CH;
    int e1 = min(e0 + CH, N_EDGES);
    for (int i = e0 + t; i < e1; i += 256) {
        atomicAdd(&lhist[dst[i] >> NPB_LOG], 1);
    }
    __syncthreads();

    // thread t owns buckets [4t, 4t+4): global bases + local scan
    int base4 = t * 4;
    int c[4], sum = 0;
#pragma unroll
    for (int j = 0; j < 4; ++j) { c[j] = lhist[base4 + j]; sum += c[j]; }
#pragma unroll
    for (int j = 0; j < 4; ++j) {
        gbase[base4 + j] = c[j] ? atomicAdd(&gcur[base4 + j], c[j]) : 0;
    }
    sscan[t] = sum;
    __syncthreads();
    for (int o = 1; o < 256; o <<= 1) {
        int x = (t >= o) ? sscan[t - o] : 0;
        __syncthreads();
        sscan[t] += x;
        __syncthreads();
    }
    int run = sscan[t] - sum;
#pragma unroll
    for (int j = 0; j < 4; ++j) {
        lexcl[base4 + j] = run;
        lhist[base4 + j] = run;   // becomes the scatter cursor
        run += c[j];
    }
    __syncthreads();

    // scatter chunk into LDS, bucket-sorted
    for (int i = e0 + t; i < e1; i += 256) {
        int d = dst[i];
        int s = src[i];
        int b = d >> NPB_LOG;
        int pos = atomicAdd(&lhist[b], 1);
        lP[pos] = ((d & (NPB - 1)) << 19) | s;
    }
    __syncthreads();

    // coalesced copy-out: wave w handles buckets w, w+4, ...
    int wave = t >> 6, lane = t & 63;
    for (int b = wave; b < NBUCK_PAD; b += 4) {
        int lb = lexcl[b];
        int cnt = lhist[b] - lb;   // cursor - base = count
        int gb = gbase[b];
        for (int j = lane; j < cnt; j += 64) {
            P[gb + j] = lP[lb + j];
        }
    }
}

// fine_sort: counting key = (node_in_bucket << 4) | (src >> 15).
// Per-node CSR segments, each node's neighbor list sub-ordered by src slice.
__global__ void fine_sort(const int* __restrict__ P, const int* __restrict__ bbase,
                          int* __restrict__ off, int* __restrict__ S) {
    __shared__ int hist[NKEY];   // 32 KB
    __shared__ int sscan[256];
    int t = threadIdx.x;
    int b = blockIdx.x;
    int bb = bbase[b];
    int be = bbase[b + 1];
    int node0 = b << NPB_LOG;

    for (int j = t; j < NKEY; j += 256) hist[j] = 0;
    __syncthreads();
    for (int j = bb + t; j < be; j += 256) {
        int p = P[j];
        int n = p >> 19;
        int s = p & 0x7FFFF;
        atomicAdd(&hist[(n << 4) | (s >> SLICE_SHIFT)], 1);
    }
    __syncthreads();

    // scan over 8192 counters: thread t owns keys [32t, 32t+32)
    int base = t * 32;
    int sum = 0;
#pragma unroll
    for (int j = 0; j < 32; ++j) sum += hist[base + j];
    sscan[t] = sum;
    __syncthreads();
    for (int o = 1; o < 256; o <<= 1) {
        int x = (t >= o) ? sscan[t - o] : 0;
        __syncthreads();
        sscan[t] += x;
        __syncthreads();
    }
    int run = sscan[t] - sum;
#pragma unroll
    for (int j = 0; j < 32; ++j) {
        int c = hist[base + j];
        hist[base + j] = run;
        run += c;
    }
    __syncthreads();

#pragma unroll
    for (int j = 0; j < 2; ++j) {
        int idx = t + j * 256;   // node_in_bucket
        int ng = node0 + idx;
        if (ng < N_NODES) off[ng] = bb + hist[idx << 4];
    }
    if (b == NBUCK - 1 && t == 0) off[N_NODES] = N_EDGES;
    __syncthreads();

    for (int j = bb + t; j < be; j += 256) {
        int p = P[j];
        int n = p >> 19;
        int s = p & 0x7FFFF;
        int pos = atomicAdd(&hist[(n << 4) | (s >> SLICE_SHIFT)], 1);
        S[bb + pos] = s;
    }
}

// count_slices: per node, pack the 16 per-slice counts as 16 u8 in an int4.
__global__ __launch_bounds__(256) void count_slices(const int* __restrict__ off,
        const int* __restrict__ S, int4* __restrict__ cnt8) {
    int i = blockIdx.x * 256 + threadIdx.x;
    if (i >= N_NODES) return;
    int b = off[i], e = off[i + 1];
    int w0 = 0, w1 = 0, w2 = 0, w3 = 0;
    for (int k = b; k < e; ++k) {
        int sl = S[k] >> SLICE_SHIFT;          // 0..15
        int inc = 1 << ((sl & 3) * 8);
        if (sl < 8) { if (sl < 4) w0 += inc; else w1 += inc; }
        else        { if (sl < 12) w2 += inc; else w3 += inc; }
    }
    cnt8[i] = make_int4(w0, w1, w2, w3);
}

// ============================================================================
// fp16 table prep: x (fp32, 4 feats) -> xh (fp16, 8 B rows)
// ============================================================================

__global__ void convert_x(const float* __restrict__ x, int2* __restrict__ xh) {
    int i = blockIdx.x * 256 + threadIdx.x;
    if (i >= N_NODES) return;
    float4 v = ((const float4*)x)[i];
    int2 r;
    r.x = pk2(v.x, v.y);
    r.y = pk2(v.z, v.w);
    xh[i] = r;
}

// ============================================================================
// Layer 1 (unphased): xh table is 4 MB ~ fits one XCD L2
// ============================================================================

__global__ __launch_bounds__(256, 4) void fused_l1(
        const int* __restrict__ off, const int* __restrict__ ssrc,
        const int2* __restrict__ xh, const float* __restrict__ x,
        const float* __restrict__ wl, const float* __restrict__ bl,
        const float* __restrict__ wr, int* __restrict__ h1) {
    __shared__ float s_wl[40];
    __shared__ float s_wr[40];
    __shared__ float s_b[10];
    if (threadIdx.x < 40) {
        s_wl[threadIdx.x] = wl[threadIdx.x];
        s_wr[threadIdx.x] = wr[threadIdx.x];
    }
    if (threadIdx.x >= 64 && threadIdx.x < 74) s_b[threadIdx.x - 64] = bl[threadIdx.x - 64];
    __syncthreads();

    int i = blockIdx.x * 256 + threadIdx.x;
    if (i >= N_NODES) return;

    int b = off[i], e = off[i + 1];
    constexpr int UN = 8;

    float acc[4] = {0.f, 0.f, 0.f, 0.f};

    int k = b;
    for (; k + UN - 1 < e; k += UN) {
        int sidx[UN];
#pragma unroll
        for (int u = 0; u < UN; ++u) sidx[u] = ssrc[k + u];
        int2 v[UN];
#pragma unroll
        for (int u = 0; u < UN; ++u) v[u] = xh[sidx[u]];
#pragma unroll
        for (int u = 0; u < UN; ++u) {
            float2 f0 = up2(v[u].x), f1 = up2(v[u].y);
            acc[0] += f0.x; acc[1] += f0.y; acc[2] += f1.x; acc[3] += f1.y;
        }
    }
    for (; k < e; ++k) {
        int2 v = xh[ssrc[k]];
        float2 f0 = up2(v.x), f1 = up2(v.y);
        acc[0] += f0.x; acc[1] += f0.y; acc[2] += f1.x; acc[3] += f1.y;
    }

    float inv = 1.f / fmaxf((float)(e - b), 1.f);
#pragma unroll
    for (int q = 0; q < 4; ++q) acc[q] *= inv;

    float4 xs = ((const float4*)x)[i];
    float xv[4] = {xs.x, xs.y, xs.z, xs.w};

    float r[10];
#pragma unroll
    for (int j = 0; j < 10; ++j) {
        float t = s_b[j];
#pragma unroll
        for (int kk = 0; kk < 4; ++kk) {
            t += s_wl[j * 4 + kk] * acc[kk] + s_wr[j * 4 + kk] * xv[kk];
        }
        r[j] = fmaxf(t, 0.f);
    }
    int4 o0;
    o0.x = pk2(r[0], r[1]); o0.y = pk2(r[2], r[3]);
    o0.z = pk2(r[4], r[5]); o0.w = pk2(r[6], r[7]);
    *(int4*)(h1 + (long)i * 8) = o0;
    h1[(long)i * 8 + 4] = pk2(r[8], r[9]);
}

// ============================================================================
// Phased layers 2 & 3: count-driven, value-independent batched scans
// ============================================================================

__device__ __forceinline__ void l2_scan_m(int& k, int m,
        const int* __restrict__ ssrc, const int* __restrict__ h1, float* acc) {
    for (; m >= 4; m -= 4, k += 4) {
        int sidx[4];
#pragma unroll
        for (int u = 0; u < 4; ++u) sidx[u] = ssrc[k + u];
        int4 v4[4];
        int v1[4];
#pragma unroll
        for (int u = 0; u < 4; ++u) {
            const int* row = h1 + (long)sidx[u] * 8;
            v4[u] = *(const int4*)row;
            v1[u] = row[4];
        }
#pragma unroll
        for (int u = 0; u < 4; ++u) {
            float2 f0 = up2(v4[u].x), f1 = up2(v4[u].y), f2 = up2(v4[u].z),
                   f3 = up2(v4[u].w), f4 = up2(v1[u]);
            acc[0] += f0.x; acc[1] += f0.y; acc[2] += f1.x; acc[3] += f1.y;
            acc[4] += f2.x; acc[5] += f2.y; acc[6] += f3.x; acc[7] += f3.y;
            acc[8] += f4.x; acc[9] += f4.y;
        }
    }
    for (; m > 0; --m, ++k) {
        const int* row = h1 + (long)ssrc[k] * 8;
        int4 v4 = *(const int4*)row;
        int v1 = row[4];
        float2 f0 = up2(v4.x), f1 = up2(v4.y), f2 = up2(v4.z), f3 = up2(v4.w), f4 = up2(v1);
        acc[0] += f0.x; acc[1] += f0.y; acc[2] += f1.x; acc[3] += f1.y;
        acc[4] += f2.x; acc[5] += f2.y; acc[6] += f3.x; acc[7] += f3.y;
        acc[8] += f4.x; acc[9] += f4.y;
    }
}

__device__ __forceinline__ void l3_scan_m(int& k, int m,
        const int* __restrict__ ssrc, const int* __restrict__ h2, float* acc) {
    for (; m >= 4; m -= 4, k += 4) {
        int sidx[4];
#pragma unroll
        for (int u = 0; u < 4; ++u) sidx[u] = ssrc[k + u];
        int4 va[4], vb[4];
        int2 vc[4];
#pragma unroll
        for (int u = 0; u < 4; ++u) {
            const int* row = h2 + (long)sidx[u] * 16;
            va[u] = *(const int4*)row;
            vb[u] = *(const int4*)(row + 4);
            vc[u] = *(const int2*)(row + 8);
        }
#pragma unroll
        for (int u = 0; u < 4; ++u) {
            float2 f;
            f = up2(va[u].x); acc[0] += f.x; acc[1] += f.y;
            f = up2(va[u].y); acc[2] += f.x; acc[3] += f.y;
            f = up2(va[u].z); acc[4] += f.x; acc[5] += f.y;
            f = up2(va[u].w); acc[6] += f.x; acc[7] += f.y;
            f = up2(vb[u].x); acc[8] += f.x; acc[9] += f.y;
            f = up2(vb[u].y); acc[10] += f.x; acc[11] += f.y;
            f = up2(vb[u].z); acc[12] += f.x; acc[13] += f.y;
            f = up2(vb[u].w); acc[14] += f.x; acc[15] += f.y;
            f = up2(vc[u].x); acc[16] += f.x; acc[17] += f.y;
            f = up2(vc[u].y); acc[18] += f.x; acc[19] += f.y;
        }
    }
    for (; m > 0; --m, ++k) {
        const int* row = h2 + (long)ssrc[k] * 16;
        int4 va = *(const int4*)row;
        int4 vb = *(const int4*)(row + 4);
        int2 vc = *(const int2*)(row + 8);
        float2 f;
        f = up2(va.x); acc[0] += f.x; acc[1] += f.y;
        f = up2(va.y); acc[2] += f.x; acc[3] += f.y;
        f = up2(va.z); acc[4] += f.x; acc[5] += f.y;
        f = up2(va.w); acc[6] += f.x; acc[7] += f.y;
        f = up2(vb.x); acc[8] += f.x; acc[9] += f.y;
        f = up2(vb.y); acc[10] += f.x; acc[11] += f.y;
        f = up2(vb.z); acc[12] += f.x; acc[13] += f.y;
        f = up2(vb.w); acc[14] += f.x; acc[15] += f.y;
        f = up2(vc.x); acc[16] += f.x; acc[17] += f.y;
        f = up2(vc.y); acc[18] += f.x; acc[19] += f.y;
    }
}

__device__ __forceinline__ void l2_tail(int n, float deg, float* acc,
        const int* __restrict__ h1, const float* s_wl, const float* s_wr,
        const float* s_b, int* __restrict__ h2) {
    if (n >= N_NODES) return;
    float inv = 1.f / fmaxf(deg, 1.f);
#pragma unroll
    for (int q = 0; q < 10; ++q) acc[q] *= inv;
    float xv[10];
    {
        const int* row = h1 + (long)n * 8;
        int4 v4 = *(const int4*)row;
        int v1 = row[4];
        float2 f0 = up2(v4.x), f1 = up2(v4.y), f2 = up2(v4.z), f3 = up2(v4.w), f4 = up2(v1);
        xv[0] = f0.x; xv[1] = f0.y; xv[2] = f1.x; xv[3] = f1.y;
        xv[4] = f2.x; xv[5] = f2.y; xv[6] = f3.x; xv[7] = f3.y;
        xv[8] = f4.x; xv[9] = f4.y;
    }
    float r[20];
#pragma unroll
    for (int j = 0; j < 20; ++j) {
        float t = s_b[j];
#pragma unroll
        for (int kk = 0; kk < 10; ++kk)
            t += s_wl[j * 10 + kk] * acc[kk] + s_wr[j * 10 + kk] * xv[kk];
        r[j] = fmaxf(t, 0.f);
    }
    int* o = h2 + (long)n * 16;
    int4 o0, o1;
    o0.x = pk2(r[0], r[1]);   o0.y = pk2(r[2], r[3]);
    o0.z = pk2(r[4], r[5]);   o0.w = pk2(r[6], r[7]);
    o1.x = pk2(r[8], r[9]);   o1.y = pk2(r[10], r[11]);
    o1.z = pk2(r[12], r[13]); o1.w = pk2(r[14], r[15]);
    *(int4*)o = o0;
    *(int4*)(o + 4) = o1;
    int2 o2;
    o2.x = pk2(r[16], r[17]); o2.y = pk2(r[18], r[19]);
    *(int2*)(o + 8) = o2;
}

__global__ __launch_bounds__(256, 4) void fused_l2p(
        const int* __restrict__ off, const int* __restrict__ ssrc,
        const int* __restrict__ h1,
        const float* __restrict__ wl, const float* __restrict__ bl,
        const float* __restrict__ wr, int* __restrict__ h2,
        const int4* __restrict__ cnt8, int* __restrict__ bar) {
    __shared__ float s_wl[200];
    __shared__ float s_wr[200];
    __shared__ float s_b[20];
    if (threadIdx.x < 200) {
        s_wl[threadIdx.x] = wl[threadIdx.x];
        s_wr[threadIdx.x] = wr[threadIdx.x];
    }
    if (threadIdx.x >= 224 && threadIdx.x < 244) s_b[threadIdx.x - 224] = bl[threadIdx.x - 224];
    __syncthreads();

    const int tg = blockIdx.x * 256 + threadIdx.x;
    const int n0 = tg, n1 = tg + HALF_T;
    int k0 = off[n0];
    float deg0 = (float)(off[n0 + 1] - k0);
    int4 c0 = cnt8[n0];
    int k1 = 0;
    float deg1 = 0.f;
    int4 c1 = make_int4(0, 0, 0, 0);
    if (n1 < N_NODES) {
        k1 = off[n1];
        deg1 = (float)(off[n1 + 1] - k1);
        c1 = cnt8[n1];
    }
    float acc0[10], acc1[10];
#pragma unroll
    for (int q = 0; q < 10; ++q) { acc0[q] = 0.f; acc1[q] = 0.f; }

    bool coop = true;
    if (threadIdx.x == 0) {
        barrier_arrive(bar, blockIdx.x);
        coop = barrier_wait(bar, ENTRY_BUDGET);
    }
    __syncthreads();

    constexpr int PH = 8;   // 2 MB of h1 per phase (2 slices)
    for (int s = 0; s < PH; ++s) {
        int cw0 = (s < 4) ? ((s < 2) ? c0.x : c0.y) : ((s < 6) ? c0.z : c0.w);
        int cw1 = (s < 4) ? ((s < 2) ? c1.x : c1.y) : ((s < 6) ? c1.z : c1.w);
        int sh = (s & 1) * 16;
        int m0 = ((cw0 >> sh) & 255) + ((cw0 >> (sh + 8)) & 255);
        int m1 = ((cw1 >> sh) & 255) + ((cw1 >> (sh + 8)) & 255);
        l2_scan_m(k0, m0, ssrc, h1, acc0);
        l2_scan_m(k1, m1, ssrc, h1, acc1);
        if (s < PH - 1) {
            if (threadIdx.x == 0) {
                int* rec = bar + (1 + s) * BAR_REC_INTS;
                barrier_arrive(rec, blockIdx.x);
                if (coop) coop = barrier_wait(rec, PHASE_BUDGET);
            }
            __syncthreads();
        }
    }
    l2_tail(n0, deg0, acc0, h1, s_wl, s_wr, s_b, h2);
    l2_tail(n1, deg1, acc1, h1, s_wl, s_wr, s_b, h2);
}

__device__ __forceinline__ void l3_tail(int n, float deg, float* acc,
        const int* __restrict__ h2, const float* s_wl, const float* s_wr,
        const float* s_b, const float* s_wc, const float* s_bc,
        float* __restrict__ out) {
    if (n >= N_NODES) return;
    float inv = 1.f / fmaxf(deg, 1.f);
#pragma unroll
    for (int q = 0; q < 20; ++q) acc[q] *= inv;
    float xv[20];
    {
        const int* row = h2 + (long)n * 16;
        int4 va = *(const int4*)row;
        int4 vb = *(const int4*)(row + 4);
        int2 vc = *(const int2*)(row + 8);
        float2 f;
        f = up2(va.x); xv[0] = f.x; xv[1] = f.y;
        f = up2(va.y); xv[2] = f.x; xv[3] = f.y;
        f = up2(va.z); xv[4] = f.x; xv[5] = f.y;
        f = up2(va.w); xv[6] = f.x; xv[7] = f.y;
        f = up2(vb.x); xv[8] = f.x; xv[9] = f.y;
        f = up2(vb.y); xv[10] = f.x; xv[11] = f.y;
        f = up2(vb.z); xv[12] = f.x; xv[13] = f.y;
        f = up2(vb.w); xv[14] = f.x; xv[15] = f.y;
        f = up2(vc.x); xv[16] = f.x; xv[17] = f.y;
        f = up2(vc.y); xv[18] = f.x; xv[19] = f.y;
    }
    float h3[20];
#pragma unroll
    for (int j = 0; j < 20; ++j) {
        float r = s_b[j];
#pragma unroll
        for (int kk = 0; kk < 20; ++kk)
            r += s_wl[j * 20 + kk] * acc[kk] + s_wr[j * 20 + kk] * xv[kk];
        h3[j] = fmaxf(r, 0.f);
    }
#pragma unroll
    for (int j = 0; j < 8; ++j) {
        float r = s_bc[j];
#pragma unroll
        for (int kk = 0; kk < 20; ++kk) r += s_wc[j * 20 + kk] * h3[kk];
        out[(long)n * 8 + j] = r;
    }
}

__global__ __launch_bounds__(256, 4) void fused_l3p(
        const int* __restrict__ off, const int* __restrict__ ssrc,
        const int* __restrict__ h2,
        const float* __restrict__ w3l, const float* __restrict__ b3,
        const float* __restrict__ w3r,
        const float* __restrict__ wc, const float* __restrict__ bc,
        float* __restrict__ out, const int4* __restrict__ cnt8,
        int* __restrict__ bar) {
    __shared__ float s_wl[400];
    __shared__ float s_wr[400];
    __shared__ float s_b[20];
    __shared__ float s_wc[160];
    __shared__ float s_bc[8];
    for (int t = threadIdx.x; t < 400; t += 256) {
        s_wl[t] = w3l[t];
        s_wr[t] = w3r[t];
    }
    if (threadIdx.x < 160) s_wc[threadIdx.x] = wc[threadIdx.x];
    if (threadIdx.x >= 192 && threadIdx.x < 212) s_b[threadIdx.x - 192] = b3[threadIdx.x - 192];
    if (threadIdx.x >= 224 && threadIdx.x < 232) s_bc[threadIdx.x - 224] = bc[threadIdx.x - 224];
    __syncthreads();

    const int tg = blockIdx.x * 256 + threadIdx.x;
    const int n0 = tg, n1 = tg + HALF_T;
    int k0 = off[n0];
    float deg0 = (float)(off[n0 + 1] - k0);
    int4 c0 = cnt8[n0];
    int k1 = 0;
    float deg1 = 0.f;
    int4 c1 = make_int4(0, 0, 0, 0);
    if (n1 < N_NODES) {
        k1 = off[n1];
        deg1 = (float)(off[n1 + 1] - k1);
        c1 = cnt8[n1];
    }
    float acc0[20], acc1[20];
#pragma unroll
    for (int q = 0; q < 20; ++q) { acc0[q] = 0.f; acc1[q] = 0.f; }

    bool coop = true;
    if (threadIdx.x == 0) {
        barrier_arrive(bar, blockIdx.x);
        coop = barrier_wait(bar, ENTRY_BUDGET);
    }
    __syncthreads();

    constexpr int PH = 16;   // 2 MB of h2 per phase (1 slice)
    for (int s = 0; s < PH; ++s) {
        int cw0 = (s < 8) ? ((s < 4) ? c0.x : c0.y) : ((s < 12) ? c0.z : c0.w);
        int cw1 = (s < 8) ? ((s < 4) ? c1.x : c1.y) : ((s < 12) ? c1.z : c1.w);
        int sh = (s & 3) * 8;
        int m0 = (cw0 >> sh) & 255;
        int m1 = (cw1 >> sh) & 255;
        l3_scan_m(k0, m0, ssrc, h2, acc0);
        l3_scan_m(k1, m1, ssrc, h2, acc1);
        if (s < PH - 1) {
            if (threadIdx.x == 0) {
                int* rec = bar + (1 + s) * BAR_REC_INTS;
                barrier_arrive(rec, blockIdx.x);
                if (coop) coop = barrier_wait(rec, PHASE_BUDGET);
            }
            __syncthreads();
        }
    }
    l3_tail(n0, deg0, acc0, h2, s_wl, s_wr, s_b, s_wc, s_bc, out);
    l3_tail(n1, deg1, acc1, h2, s_wl, s_wr, s_b, s_wc, s_bc, out);
}

// ============================================================================
// Path B (fallback, small ws): float-atomic version
// ============================================================================

__global__ void deg_kernel(const int* __restrict__ dst, int* __restrict__ deg) {
    int i = blockIdx.x * blockDim.x + threadIdx.x;
    if (i < N_EDGES) atomicAdd(&deg[dst[i]], 1);
}

template <int F>
__global__ void edge_agg(const int* __restrict__ src, const int* __restrict__ dst,
                         const float* __restrict__ h, float* __restrict__ agg) {
    int i = blockIdx.x * blockDim.x + threadIdx.x;
    if (i >= N_EDGES) return;
    int s = src[i];
    int d = dst[i];
    const float* hs = h + (long)s * F;
    float* ad = agg + (long)d * F;
#pragma unroll
    for (int f = 0; f < F; ++f) atomicAdd(&ad[f], hs[f]);
}

template <int FIN, int FOUT>
__global__ void node_apply(const float* __restrict__ agg, const float* __restrict__ hin,
                           const int* __restrict__ deg, const float* __restrict__ wl,
                           const float* __restrict__ bl, const float* __restrict__ wr,
                           float* __restrict__ hout) {
    __shared__ float s_wl[FOUT * FIN];
    __shared__ float s_wr[FOUT * FIN];
    __shared__ float s_b[FOUT];
    for (int t = threadIdx.x; t < FOUT * FIN; t += blockDim.x) {
        s_wl[t] = wl[t];
        s_wr[t] = wr[t];
    }
    for (int t = threadIdx.x; t < FOUT; t += blockDim.x) s_b[t] = bl[t];
    __syncthreads();
    int i = blockIdx.x * blockDim.x + threadIdx.x;
    if (i >= N_NODES) return;
    float inv = 1.0f / fmaxf((float)deg[i], 1.0f);
    float a[FIN], xv[FIN];
#pragma unroll
    for (int kk = 0; kk < FIN; ++kk) {
        a[kk] = agg[(long)i * FIN + kk] * inv;
        xv[kk] = hin[(long)i * FIN + kk];
    }
#pragma unroll
    for (int j = 0; j < FOUT; ++j) {
        float r = s_b[j];
#pragma unroll
        for (int kk = 0; kk < FIN; ++kk) r += s_wl[j * FIN + kk] * a[kk] + s_wr[j * FIN + kk] * xv[kk];
        hout[(long)i * FOUT + j] = fmaxf(r, 0.f);
    }
}

__global__ void node_final_old(const float* __restrict__ agg, const float* __restrict__ hin,
                               const int* __restrict__ deg, const float* __restrict__ w3l,
                               const float* __restrict__ b3, const float* __restrict__ w3r,
                               const float* __restrict__ wc, const float* __restrict__ bc,
                               float* __restrict__ out) {
    __shared__ float s_wl[400];
    __shared__ float s_wr[400];
    __shared__ float s_b[20];
    __shared__ float s_wc[160];
    __shared__ float s_bc[8];
    for (int t = threadIdx.x; t < 400; t += blockDim.x) {
        s_wl[t] = w3l[t];
        s_wr[t] = w3r[t];
    }
    for (int t = threadIdx.x; t < 160; t += blockDim.x) s_wc[t] = wc[t];
    for (int t = threadIdx.x; t < 20; t += blockDim.x) s_b[t] = b3[t];
    for (int t = threadIdx.x; t < 8; t += blockDim.x) s_bc[t] = bc[t];
    __syncthreads();
    int i = blockIdx.x * blockDim.x + threadIdx.x;
    if (i >= N_NODES) return;
    float inv = 1.0f / fmaxf((float)deg[i], 1.0f);
    float a[20], xv[20];
#pragma unroll
    for (int kk = 0; kk < 20; ++kk) {
        a[kk] = agg[(long)i * 20 + kk] * inv;
        xv[kk] = hin[(long)i * 20 + kk];
    }
    float h3[20];
#pragma unroll
    for (int j = 0; j < 20; ++j) {
        float r = s_b[j];
#pragma unroll
        for (int kk = 0; kk < 20; ++kk) r += s_wl[j * 20 + kk] * a[kk] + s_wr[j * 20 + kk] * xv[kk];
        h3[j] = fmaxf(r, 0.f);
    }
#pragma unroll
    for (int j = 0; j < 8; ++j) {
        float r = s_bc[j];
#pragma unroll
        for (int kk = 0; kk < 20; ++kk) r += s_wc[j * 20 + kk] * h3[kk];
        out[(long)i * 8 + j] = r;
    }
}

// ============================================================================

extern "C" void kernel_launch(void* const* d_in, const int* in_sizes, int n_in,
                              void* d_out, int out_size, void* d_ws, size_t ws_size,
                              hipStream_t stream) {
    const float* x = (const float*)d_in[0];
    const int* ei = (const int*)d_in[1];  // [2, E]: src row then dst row
    const float* w1l = (const float*)d_in[2];
    const float* b1 = (const float*)d_in[3];
    const float* w1r = (const float*)d_in[4];
    const float* w2l = (const float*)d_in[5];
    const float* b2 = (const float*)d_in[6];
    const float* w2r = (const float*)d_in[7];
    const float* w3l = (const float*)d_in[8];
    const float* b3 = (const float*)d_in[9];
    const float* w3r = (const float*)d_in[10];
    const float* wc = (const float*)d_in[11];
    const float* bc = (const float*)d_in[12];
    float* out = (float*)d_out;

    const int* src = ei;
    const int* dst = ei + N_EDGES;

    const int BT = 256;
    dim3 blk(BT);
    dim3 egrid((N_EDGES + BT - 1) / BT);
    dim3 ngrid(NB);

    // ---- Path A v9 layout (bytes):
    // off    [0,          2,000,128)   500001 ints (padded)
    // bbase  [2,000,128,  2,004,352)   1025 ints (padded)
    // gcur   [2,004,352,  2,008,448)   1024 ints
    // P      [2,008,448,  66,008,448)  16M packed ints (dead after fine_sort)
    //   xh   [2,008,448,  6,008,448)   overlay: 500K x 8 B fp16 rows
    //   h1   [6,008,448, 22,008,448)   overlay: 500K x 32 B fp16 rows
    //   h2   [22,008,448, 54,008,448)  overlay: 500K x 64 B fp16 rows
    //   bar  [54,008,448, 54,106,752)  overlay: 24 x 4 KB barrier records
    //   cnt8 [54,206,464, 62,206,464)  overlay: 500K x 16 B slice counts
    // S      [66,008,448, 130,008,448) 16M sorted src
    const size_t NEED_A = 130008448;

    if (ws_size >= NEED_A) {
        char* ws = (char*)d_ws;
        int* off = (int*)ws;
        int* bbase = (int*)(ws + 2000128);
        int* gcur = (int*)(ws + 2004352);
        int* P = (int*)(ws + 2008448);
        int2* xh = (int2*)(ws + 2008448);
        int* h1 = (int*)(ws + 6008448);
        int* h2 = (int*)(ws + 22008448);
        int* bar2 = (int*)(ws + 54008448);               // 8 records (entry + 7)
        int* bar3 = bar2 + 8 * BAR_REC_INTS;             // 16 records (entry + 15)
        int4* cnt8 = (int4*)(ws + 54206464);
        int* S = (int*)(ws + 66008448);

        hipMemsetAsync(gcur, 0, NBUCK_PAD * sizeof(int), stream);
        bucket_hist<<<1024, blk, 0, stream>>>(dst, gcur);
        bucket_scan<<<1, blk, 0, stream>>>(gcur, bbase);
        bucket_scatter<<<NSB, blk, 0, stream>>>(src, dst, gcur, P);
        fine_sort<<<NBUCK, blk, 0, stream>>>(P, bbase, off, S);

        // P is dead after fine_sort; zero the barrier overlay (stream-ordered)
        hipMemsetAsync(bar2, 0, 24 * BAR_REC_INTS * sizeof(int), stream);

        count_slices<<<ngrid, blk, 0, stream>>>(off, S, cnt8);
        convert_x<<<ngrid, blk, 0, stream>>>(x, xh);
        fused_l1<<<ngrid, blk, 0, stream>>>(off, S, xh, x, w1l, b1, w1r, h1);
        fused_l2p<<<GRID_BLK, blk, 0, stream>>>(off, S, h1, w2l, b2, w2r, h2, cnt8, bar2);
        fused_l3p<<<GRID_BLK, blk, 0, stream>>>(off, S, h2, w3l, b3, w3r, wc, bc, out, cnt8, bar3);
    } else {
        // fallback: float-atomic path (needs 102 MB)
        char* ws = (char*)d_ws;
        int* deg = (int*)ws;
        float* agg = (float*)(ws + 2000000);
        float* h1 = (float*)(ws + 42000000);
        float* h2 = (float*)(ws + 62000000);

        hipMemsetAsync(deg, 0, (size_t)N_NODES * sizeof(int), stream);
        deg_kernel<<<egrid, blk, 0, stream>>>(dst, deg);

        hipMemsetAsync(agg, 0, (size_t)N_NODES * 4 * sizeof(float), stream);
        edge_agg<4><<<egrid, blk, 0, stream>>>(src, dst, x, agg);
        node_apply<4, 10><<<ngrid, blk, 0, stream>>>(agg, x, deg, w1l, b1, w1r, h1);

        hipMemsetAsync(agg, 0, (size_t)N_NODES * 10 * sizeof(float), stream);
        edge_agg<10><<<egrid, blk, 0, stream>>>(src, dst, h1, agg);
        node_apply<10, 20><<<ngrid, blk, 0, stream>>>(agg, h1, deg, w2l, b2, w2r, h2);

        hipMemsetAsync(agg, 0, (size_t)N_NODES * 20 * sizeof(float), stream);
        edge_agg<20><<<egrid, blk, 0, stream>>>(src, dst, h2, agg);
        node_final_old<<<ngrid, blk, 0, stream>>>(agg, h2, deg, w3l, b3, w3r, wc, bc, out);
    }
}